// Round 1
// baseline (566.571 us; speedup 1.0000x reference)
//
#include <hip/hip_runtime.h>
#include <math.h>

// LSTM "learned optimizer" scan over N = 1M elements, H=20, batch=1.
// Parallelized via contraction-based chunking: each chunk of CL outputs is
// computed by 4 lanes starting from zero state WU steps early (warm-up).
// Weights staged in LDS, permuted so each lane streams its 20 gate-row
// coefficients per k as 5 float4 reads (conflict-free, broadcast across chunks).

#define CL    64            // outputs per chunk
#define WU    96            // warm-up steps (contraction kills init-state error)
#define BLOCK 256
#define CPB   (BLOCK / 4)   // 64 chunks per block
#define HDIM  20
#define NROW  80            // 4 gates * HDIM

__device__ __forceinline__ float sigm(float x) {
    return __fdividef(1.0f, 1.0f + __expf(-x));
}
__device__ __forceinline__ float tanh_fast(float x) {
    // 1 - 2/(1+e^{2x}); saturates correctly for |x| large (exp->inf/0)
    return 1.0f - __fdividef(2.0f, 1.0f + __expf(2.0f * x));
}

__global__ __launch_bounds__(BLOCK) void lstm_scan_kernel(
    const float* __restrict__ inputs, int N,
    const float* __restrict__ cW_ih, const float* __restrict__ cW_hh,
    const float* __restrict__ cb_ih, const float* __restrict__ cb_hh,
    const float* __restrict__ cfc_w, const float* __restrict__ cfc_b,
    const float* __restrict__ fW_ih, const float* __restrict__ fW_hh,
    const float* __restrict__ fb_ih, const float* __restrict__ fb_hh,
    const float* __restrict__ ffc_w, const float* __restrict__ ffc_b,
    const int*   __restrict__ is_conv,
    float* __restrict__ out)
{
    // WT layout: 23 rows of 80 floats. Row k<20: W_hh column k, permuted so
    // position p = r*20 + (unit_local*4 + gate) for role r (lane&3).
    // Row 20: W_ih[:,0], row 21: W_ih[:,1], row 22: b_ih+b_hh (same perm).
    __shared__ float WT[23 * NROW];
    __shared__ float fcw_s[HDIM];
    __shared__ float fcb_s;

    const bool conv = (is_conv[0] != 0);
    const float* W_ih = conv ? cW_ih : fW_ih;
    const float* W_hh = conv ? cW_hh : fW_hh;
    const float* b_ih = conv ? cb_ih : fb_ih;
    const float* b_hh = conv ? cb_hh : fb_hh;
    const float* fc_w = conv ? cfc_w : ffc_w;
    const float* fc_b = conv ? cfc_b : ffc_b;

    const int tid = threadIdx.x;
    for (int idx = tid; idx < 23 * NROW; idx += BLOCK) {
        const int k = idx / NROW, p = idx % NROW;
        const int r = p / 20, q = p % 20, ul = q >> 2, g = q & 3;
        const int row = g * 20 + r * 5 + ul;   // gate-major row index in W_hh
        float v;
        if (k < 20)       v = W_hh[row * 20 + k];
        else if (k == 20) v = W_ih[row * 2 + 0];
        else if (k == 21) v = W_ih[row * 2 + 1];
        else              v = b_ih[row] + b_hh[row];
        WT[k * NROW + p] = v;
    }
    if (tid < HDIM) fcw_s[tid] = fc_w[tid];
    if (tid == 0)   fcb_s = fc_b[0];
    __syncthreads();

    const int lane  = tid & 63;
    const int r     = tid & 3;              // role: hidden units r*5..r*5+4
    const int base  = lane & ~3;            // first lane of this 4-lane group
    const int chunk = blockIdx.x * CPB + (tid >> 2);
    const int gstart = chunk * CL;
    if (gstart >= N) return;
    const int tstart = (gstart - WU) > 0 ? (gstart - WU) : 0;
    const int tend   = (gstart + CL) < N ? (gstart + CL) : N;

    float h[HDIM];
    float c[5], hl[5], fcw_l[5];
#pragma unroll
    for (int k = 0; k < HDIM; ++k) h[k] = 0.0f;
#pragma unroll
    for (int j = 0; j < 5; ++j) { c[j] = 0.0f; hl[j] = 0.0f; }
#pragma unroll
    for (int j = 0; j < 5; ++j) fcw_l[j] = fcw_s[r * 5 + j];
    const float fcb = fcb_s;

    const float4* WT4 = (const float4*)WT;  // 20 float4 per row
    const int pb = r * 5;                   // this lane's float4 base in a row

    for (int t = tstart; t < tend; ++t) {
        // x_t = [log, sign]; log clamped BEFORE sign (torch semantics)
        const float v  = inputs[t];
        float lg = __logf(fabsf(v) + 1e-7f) * 0.14285714285714285f; // /7
        lg = fmaxf(lg, -1.0f);
        float sg = fminf(fmaxf(lg * 1096.6331584284585f, -1.0f), 1.0f); // *e^7

        // gate pre-activations for this lane's 20 rows
        float acc[20];
#pragma unroll
        for (int j = 0; j < 5; ++j) {
            const float4 wb = WT4[22 * 20 + pb + j];   // bias
            const float4 w0 = WT4[20 * 20 + pb + j];   // W_ih[:,0]
            const float4 w1 = WT4[21 * 20 + pb + j];   // W_ih[:,1]
            acc[4*j+0] = fmaf(w1.x, sg, fmaf(w0.x, lg, wb.x));
            acc[4*j+1] = fmaf(w1.y, sg, fmaf(w0.y, lg, wb.y));
            acc[4*j+2] = fmaf(w1.z, sg, fmaf(w0.z, lg, wb.z));
            acc[4*j+3] = fmaf(w1.w, sg, fmaf(w0.w, lg, wb.w));
        }
#pragma unroll
        for (int k = 0; k < HDIM; ++k) {
            const float hk = h[k];
#pragma unroll
            for (int j = 0; j < 5; ++j) {
                const float4 w = WT4[k * 20 + pb + j];
                acc[4*j+0] = fmaf(w.x, hk, acc[4*j+0]);
                acc[4*j+1] = fmaf(w.y, hk, acc[4*j+1]);
                acc[4*j+2] = fmaf(w.z, hk, acc[4*j+2]);
                acc[4*j+3] = fmaf(w.w, hk, acc[4*j+3]);
            }
        }

        // activations + state update for this lane's 5 units
        float p = 0.0f;
#pragma unroll
        for (int j = 0; j < 5; ++j) {
            const float i_ = sigm(acc[4*j+0]);
            const float f_ = sigm(acc[4*j+1]);
            const float g_ = tanh_fast(acc[4*j+2]);
            const float o_ = sigm(acc[4*j+3]);
            const float cn = fmaf(f_, c[j], i_ * g_);
            c[j] = cn;
            const float hn = o_ * tanh_fast(cn);
            hl[j] = hn;
            p = fmaf(fcw_l[j], hn, p);
        }

        // fc output: reduce partial dot over the 4-lane group
        p += __shfl_down(p, 2, 4);
        p += __shfl_down(p, 1, 4);
        if (r == 0 && t >= gstart) out[t] = p + fcb;

        // broadcast new h (wave-synchronous, groups never cross a wave)
#pragma unroll
        for (int rr = 0; rr < 4; ++rr) {
#pragma unroll
            for (int j = 0; j < 5; ++j)
                h[rr * 5 + j] = __shfl(hl[j], base + rr, 64);
        }
    }
}

extern "C" void kernel_launch(void* const* d_in, const int* in_sizes, int n_in,
                              void* d_out, int out_size, void* d_ws, size_t ws_size,
                              hipStream_t stream) {
    const float* inputs = (const float*)d_in[0];
    const float* cW_ih  = (const float*)d_in[1];
    const float* cW_hh  = (const float*)d_in[2];
    const float* cb_ih  = (const float*)d_in[3];
    const float* cb_hh  = (const float*)d_in[4];
    const float* cfc_w  = (const float*)d_in[5];
    const float* cfc_b  = (const float*)d_in[6];
    const float* fW_ih  = (const float*)d_in[7];
    const float* fW_hh  = (const float*)d_in[8];
    const float* fb_ih  = (const float*)d_in[9];
    const float* fb_hh  = (const float*)d_in[10];
    const float* ffc_w  = (const float*)d_in[11];
    const float* ffc_b  = (const float*)d_in[12];
    const int*   is_conv = (const int*)d_in[13];
    float* out = (float*)d_out;

    const int N = in_sizes[0];
    const int C = (N + CL - 1) / CL;
    const int blocks = (C + CPB - 1) / CPB;
    lstm_scan_kernel<<<blocks, BLOCK, 0, stream>>>(
        inputs, N, cW_ih, cW_hh, cb_ih, cb_hh, cfc_w, cfc_b,
        fW_ih, fW_hh, fb_ih, fb_hh, ffc_w, ffc_b, is_conv, out);
}

// Round 2
// 182.163 us; speedup vs baseline: 3.1102x; 3.1102x over previous
//
#include <hip/hip_runtime.h>
#include <math.h>

// LSTM learned-optimizer scan, MFMA formulation.
// Per wave: 16 chunks (N-dim), per step one 80x23 x 23x16 matmul as
// 5x mfma_f32_16x16x32_f16. A (weights) resident in VGPRs, rows permuted so
// C/D fragment reg j = gate j (i,f,g,o) of unit (laneq + 4*tile) — activation
// happens in-place on the owning lane. h round-trips via per-wave LDS (f16).
// Gate rows prescaled by log2(e) (2*log2(e) for g) so exp2 is used directly.

#define CL    64            // outputs per chunk
#define WU    96            // warm-up steps (contraction kills init-state error)
#define BLOCK 256
#define WAVES_PB 4
#define CH_PER_WAVE 16
#define CH_PER_BLOCK (WAVES_PB * CH_PER_WAVE)
#define KSTR  24            // f16 per chunk row in LDS (23 used: 20 h + lg + sg + one)
#define HREG  400           // f16 per wave region (16*24=384 + overrun pad)

typedef _Float16 half8 __attribute__((ext_vector_type(8)));
typedef float   float4_t __attribute__((ext_vector_type(4)));

#define L2E   1.4426950408889634f
#define L2E2  2.8853900817779268f

__device__ __forceinline__ int clampi(int v, int lo, int hi) {
    return v < lo ? lo : (v > hi ? hi : v);
}

__global__ __launch_bounds__(BLOCK) void lstm_mfma_kernel(
    const float* __restrict__ inputs, int N,
    const float* __restrict__ cW_ih, const float* __restrict__ cW_hh,
    const float* __restrict__ cb_ih, const float* __restrict__ cb_hh,
    const float* __restrict__ cfc_w, const float* __restrict__ cfc_b,
    const float* __restrict__ fW_ih, const float* __restrict__ fW_hh,
    const float* __restrict__ fb_ih, const float* __restrict__ fb_hh,
    const float* __restrict__ ffc_w, const float* __restrict__ ffc_b,
    const int*   __restrict__ is_conv,
    float* __restrict__ out)
{
    __shared__ _Float16 hbuf[WAVES_PB * HREG];

    const bool conv = (is_conv[0] != 0);
    const float* W_ih = conv ? cW_ih : fW_ih;
    const float* W_hh = conv ? cW_hh : fW_hh;
    const float* b_ih = conv ? cb_ih : fb_ih;
    const float* b_hh = conv ? cb_hh : fb_hh;
    const float* fc_w = conv ? cfc_w : ffc_w;
    const float* fc_b = conv ? cfc_b : ffc_b;

    const int tid  = threadIdx.x;
    const int lane = tid & 63;
    const int wid  = tid >> 6;
    const int cloc = lane & 15;       // chunk column within wave (= MFMA n / A row m)
    const int q    = lane >> 4;       // quad: A/B k-group, C/D row-group

    // Zero the h staging region (also gives deterministic zero-init warmup state).
    {
        int* hz = (int*)hbuf;
        for (int i = tid; i < (WAVES_PB * HREG) / 2; i += BLOCK) hz[i] = 0;
    }
    __syncthreads();
    _Float16* hw = hbuf + wid * HREG;
    if (q == 0) hw[cloc * KSTR + 22] = (_Float16)1.0f;   // bias row B[k=22] = 1

    // ---- A fragments: 5 tiles of 16x32, resident in VGPRs ----
    // Logical MFMA row m of tile t -> original gate-row R = (m&3)*20 + (m>>2) + 4t
    // (gate order i,f,g,o). A layout: lane holds row m=cloc, k = q*8 + j.
    // k: 0..19 = W_hh cols, 20/21 = W_ih cols (lg/sg), 22 = bias, 23..31 = 0.
    half8 afrag[5];
    {
        const int m = cloc;
        const int gate = m & 3;
        const float scale = (gate == 2) ? L2E2 : L2E;
#pragma unroll
        for (int t = 0; t < 5; ++t) {
            const int R = gate * 20 + (m >> 2) + 4 * t;
#pragma unroll
            for (int j = 0; j < 8; ++j) {
                const int k = q * 8 + j;
                float val;
                if (k < 20)       val = W_hh[R * 20 + k];
                else if (k == 20) val = W_ih[R * 2 + 0];
                else if (k == 21) val = W_ih[R * 2 + 1];
                else if (k == 22) val = b_ih[R] + b_hh[R];
                else              val = 0.0f;
                afrag[t][j] = (_Float16)(val * scale);
            }
        }
    }

    // C/D: col = lane&15 = chunk, row = q*4 + reg -> gate=reg, unit = q + 4*tile.
    float fcw_l[5];
#pragma unroll
    for (int t = 0; t < 5; ++t) fcw_l[t] = fc_w[q + 4 * t];
    const float fcb = fc_b[0];

    const int C = (N + CL - 1) / CL;
    const int chunk  = (blockIdx.x * WAVES_PB + wid) * CH_PER_WAVE + cloc;
    const int gstart = chunk * CL;
    const bool live  = chunk < C;

    float cst[5] = {0.f, 0.f, 0.f, 0.f, 0.f};

    const int hwr = cloc * KSTR;                 // this chunk's LDS row base
    float xcur = inputs[clampi(gstart - WU, 0, N - 1)];

    const int ST = WU + CL;
    for (int s = 0; s < ST; ++s) {
        const int t = gstart - WU + s;
        // prefetch next step's input (hides global latency across the step)
        const float xnext = inputs[clampi(t + 1, 0, N - 1)];

        // x_t features; log clamped BEFORE sign (torch semantics)
        float lg = __builtin_amdgcn_logf(fabsf(xcur) + 1e-7f) * 0.09902102579427789f; // log2*ln2/7
        lg = fmaxf(lg, -1.0f);
        const float sg = fminf(fmaxf(lg * 1096.6331584284585f, -1.0f), 1.0f);
        if (q == 0) {
            hw[hwr + 20] = (_Float16)lg;
            hw[hwr + 21] = (_Float16)sg;
        }

        // B fragment: k = q*8 + j for column cloc (16B aligned, conflict-free)
        const half8 bfrag = *(const half8*)&hw[hwr + 8 * q];

        float4_t d0 = __builtin_amdgcn_mfma_f32_16x16x32_f16(afrag[0], bfrag, (float4_t){0.f,0.f,0.f,0.f}, 0, 0, 0);
        float4_t d1 = __builtin_amdgcn_mfma_f32_16x16x32_f16(afrag[1], bfrag, (float4_t){0.f,0.f,0.f,0.f}, 0, 0, 0);
        float4_t d2 = __builtin_amdgcn_mfma_f32_16x16x32_f16(afrag[2], bfrag, (float4_t){0.f,0.f,0.f,0.f}, 0, 0, 0);
        float4_t d3 = __builtin_amdgcn_mfma_f32_16x16x32_f16(afrag[3], bfrag, (float4_t){0.f,0.f,0.f,0.f}, 0, 0, 0);
        float4_t d4 = __builtin_amdgcn_mfma_f32_16x16x32_f16(afrag[4], bfrag, (float4_t){0.f,0.f,0.f,0.f}, 0, 0, 0);

        // Exact-start chunks: state entering t==0 must be zero -> zero what
        // the t==-1 step writes (h and c). Per-lane uniform-in-s arithmetic.
        const float keep = (gstart + s == WU - 1) ? 0.0f : 1.0f;

        float psum = 0.0f;
        const float4_t dd[5] = {d0, d1, d2, d3, d4};
#pragma unroll
        for (int tt = 0; tt < 5; ++tt) {
            // d[j]: j=0:i, 1:f, 2:g, 3:o ; i,f,o prescaled by log2e, g by 2log2e
            const float ei = __builtin_amdgcn_exp2f(-dd[tt][0]);
            const float ef = __builtin_amdgcn_exp2f(-dd[tt][1]);
            const float eg = __builtin_amdgcn_exp2f(-dd[tt][2]);
            const float eo = __builtin_amdgcn_exp2f(-dd[tt][3]);
            const float f_ = __builtin_amdgcn_rcpf(1.0f + ef);           // sigmoid(f)
            // i*tanh-arg product shares one rcp: i*g = (1-eg)/((1+ei)(1+eg))
            const float ig = (1.0f - eg) * __builtin_amdgcn_rcpf((1.0f + ei) * (1.0f + eg));
            const float cn = fmaf(f_, cst[tt], ig) * keep;
            cst[tt] = cn;
            // h = sigmoid(o)*tanh(c) = (1-ec)/((1+eo)(1+ec)), ec = exp2(-2log2e*c)
            const float ec = __builtin_amdgcn_exp2f(cn * -L2E2);
            const float hn = (1.0f - ec) * __builtin_amdgcn_rcpf((1.0f + eo) * (1.0f + ec)) * keep;
            psum = fmaf(fcw_l[tt], hn, psum);
            hw[hwr + q + 4 * tt] = (_Float16)hn;   // unit = q + 4*tt
        }

        // fc: sum partials over the 4 quads (lanes l, l^16, l^32, l^48)
        psum += __shfl_xor(psum, 16);
        psum += __shfl_xor(psum, 32);
        if (s >= WU && q == 0 && live) out[gstart + (s - WU)] = psum + fcb;

        xcur = xnext;
    }
}

extern "C" void kernel_launch(void* const* d_in, const int* in_sizes, int n_in,
                              void* d_out, int out_size, void* d_ws, size_t ws_size,
                              hipStream_t stream) {
    const float* inputs = (const float*)d_in[0];
    const float* cW_ih  = (const float*)d_in[1];
    const float* cW_hh  = (const float*)d_in[2];
    const float* cb_ih  = (const float*)d_in[3];
    const float* cb_hh  = (const float*)d_in[4];
    const float* cfc_w  = (const float*)d_in[5];
    const float* cfc_b  = (const float*)d_in[6];
    const float* fW_ih  = (const float*)d_in[7];
    const float* fW_hh  = (const float*)d_in[8];
    const float* fb_ih  = (const float*)d_in[9];
    const float* fb_hh  = (const float*)d_in[10];
    const float* ffc_w  = (const float*)d_in[11];
    const float* ffc_b  = (const float*)d_in[12];
    const int*   is_conv = (const int*)d_in[13];
    float* out = (float*)d_out;

    const int N = in_sizes[0];
    const int C = (N + CL - 1) / CL;
    const int blocks = (C + CH_PER_BLOCK - 1) / CH_PER_BLOCK;
    lstm_mfma_kernel<<<blocks, BLOCK, 0, stream>>>(
        inputs, N, cW_ih, cW_hh, cb_ih, cb_hh, cfc_w, cfc_b,
        fW_ih, fW_hh, fb_ih, fb_hh, ffc_w, ffc_b, is_conv, out);
}

// Round 3
// 162.304 us; speedup vs baseline: 3.4908x; 1.1224x over previous
//
#include <hip/hip_runtime.h>
#include <math.h>

// LSTM learned-optimizer scan, MFMA formulation v2.
// Per wave: 16 chunks; per step one 96x32 x 32x16 f16 matmul as 6 MFMA tiles
// (5 gate tiles + 1 fc tile). Weights resident in VGPRs (launch_bounds(.,2)
// prevents AGPR parking). h exchanged via per-wave LDS: each lane writes its
// 5 h values as one aligned b64+b16; the wave's B-fragment read is one
// contiguous conflict-free 1KB ds_read_b128. Outputs come out of the fc tile
// one step late and are stored as dwordx4 every 4 steps.

#define CL    32            // outputs per chunk
#define WU    83            // warm-up steps (83 ≡ 3 mod 4 so outputs align to groups)
#define ST    (WU + CL + 1) // 116 steps, %4 == 0
#define BLOCK 256
#define WAVES_PB 4
#define KSTR  32            // f16 per chunk-row in LDS (k=0..19 h, 20 lg, 21 sg, 22 bias, 23..31 zero)
#define HREG  (16 * KSTR)   // halves per wave region

typedef _Float16 half8 __attribute__((ext_vector_type(8)));
typedef _Float16 half4 __attribute__((ext_vector_type(4)));
typedef _Float16 half2 __attribute__((ext_vector_type(2)));
typedef float  float4_t __attribute__((ext_vector_type(4)));

#define L2E   1.4426950408889634f
#define L2E2  2.8853900817779268f

__device__ __forceinline__ int clampi(int v, int lo, int hi) {
    return v < lo ? lo : (v > hi ? hi : v);
}

// Per-tile activation: d = [i,f,g,o] pre-scaled by log2e (g by 2*log2e).
#define ACT(dv, cv, hv) do {                                                   \
    const float ei = __builtin_amdgcn_exp2f(-(dv)[0]);                         \
    const float ef = __builtin_amdgcn_exp2f(-(dv)[1]);                         \
    const float eg = __builtin_amdgcn_exp2f(-(dv)[2]);                         \
    const float eo = __builtin_amdgcn_exp2f(-(dv)[3]);                         \
    const float f_ = __builtin_amdgcn_rcpf(1.0f + ef);                         \
    const float ig = (1.0f - eg) * __builtin_amdgcn_rcpf((1.0f + ei) * (1.0f + eg)); \
    float cn = fmaf(f_, (cv), ig);                                             \
    if (EARLY) cn *= keep;                                                     \
    (cv) = cn;                                                                 \
    const float ec = __builtin_amdgcn_exp2f(cn * -L2E2);                       \
    float hh = (1.0f - ec) * __builtin_amdgcn_rcpf((1.0f + eo) * (1.0f + ec)); \
    if (EARLY) hh *= keep;                                                     \
    (hv) = hh;                                                                 \
} while (0)

template<bool EARLY>
__device__ __forceinline__ void scan_loop(
    const float* __restrict__ inputs, int N,
    _Float16* hw, int hwr,
    half8 a0, half8 a1, half8 a2, half8 a3, half8 a4, half8 a5,
    int gstart, int q, bool qzero, bool live,
    float* __restrict__ out)
{
    float c0 = 0.f, c1 = 0.f, c2 = 0.f, c3 = 0.f, c4 = 0.f;
    float xcur = inputs[clampi(gstart - WU, 0, N - 1)];
    const float4_t zacc = {0.f, 0.f, 0.f, 0.f};

    for (int su = 0; su < ST; su += 4) {
        float4_t og;
#pragma unroll
        for (int k4 = 0; k4 < 4; ++k4) {
            const int s = su + k4;
            const float xnext = inputs[clampi(gstart - WU + s + 1, 0, N - 1)];

            // x_t features; log clamped BEFORE sign (torch semantics)
            float lg = __builtin_amdgcn_logf(fabsf(xcur) + 1e-7f) * 0.09902102579427789f; // log2 * ln2/7
            lg = fmaxf(lg, -1.0f);
            const float sg = fminf(fmaxf(lg * 1096.6331584284585f, -1.0f), 1.0f);
            if (qzero) *(half2*)&hw[hwr + 20] = (half2){(_Float16)lg, (_Float16)sg};

            // B fragment: contiguous conflict-free b128 (k = 8q..8q+7)
            const half8 b = *(const half8*)&hw[hwr + 8 * q];

            const float4_t d0 = __builtin_amdgcn_mfma_f32_16x16x32_f16(a0, b, zacc, 0, 0, 0);
            const float4_t d1 = __builtin_amdgcn_mfma_f32_16x16x32_f16(a1, b, zacc, 0, 0, 0);
            const float4_t d2 = __builtin_amdgcn_mfma_f32_16x16x32_f16(a2, b, zacc, 0, 0, 0);
            const float4_t d3 = __builtin_amdgcn_mfma_f32_16x16x32_f16(a3, b, zacc, 0, 0, 0);
            const float4_t d4 = __builtin_amdgcn_mfma_f32_16x16x32_f16(a4, b, zacc, 0, 0, 0);
            const float4_t d5 = __builtin_amdgcn_mfma_f32_16x16x32_f16(a5, b, zacc, 0, 0, 0);

            float keep = 1.0f;
            if (EARLY) keep = (gstart + s == WU - 1) ? 0.0f : 1.0f;

            float h0, h1, h2, h3, h4;
            ACT(d0, c0, h0);
            ACT(d1, c1, h1);
            ACT(d2, c2, h2);
            ACT(d3, c3, h3);
            ACT(d4, c4, h4);

            // h units: lane owns 4q..4q+3 (aligned b64) and 16+q (b16)
            *(half4*)&hw[hwr + 4 * q] =
                (half4){(_Float16)h0, (_Float16)h1, (_Float16)h2, (_Float16)h3};
            hw[hwr + 16 + q] = (_Float16)h4;

            og[k4] = d5[0];    // out[t-1] = fc_w . h_{t-1} + fc_b (rows 1..15 unused)
            xcur = xnext;
        }
        // outputs start at s = WU+1 = 84 (group-aligned)
        if (su >= WU + 1) {
            if (qzero && live)
                *(float4_t*)(out + (gstart + su - (WU + 1))) = og;
        }
    }
}

__global__ __launch_bounds__(BLOCK, 2) void lstm_mfma_kernel(
    const float* __restrict__ inputs, int N,
    const float* __restrict__ cW_ih, const float* __restrict__ cW_hh,
    const float* __restrict__ cb_ih, const float* __restrict__ cb_hh,
    const float* __restrict__ cfc_w, const float* __restrict__ cfc_b,
    const float* __restrict__ fW_ih, const float* __restrict__ fW_hh,
    const float* __restrict__ fb_ih, const float* __restrict__ fb_hh,
    const float* __restrict__ ffc_w, const float* __restrict__ ffc_b,
    const int*   __restrict__ is_conv,
    float* __restrict__ out)
{
    __shared__ _Float16 hbuf[WAVES_PB * HREG];   // 4 KiB

    const bool conv = (is_conv[0] != 0);
    const float* W_ih = conv ? cW_ih : fW_ih;
    const float* W_hh = conv ? cW_hh : fW_hh;
    const float* b_ih = conv ? cb_ih : fb_ih;
    const float* b_hh = conv ? cb_hh : fb_hh;
    const float* fc_w = conv ? cfc_w : ffc_w;
    const float* fc_b = conv ? cfc_b : ffc_b;

    const int tid  = threadIdx.x;
    const int lane = tid & 63;
    const int wid  = tid >> 6;
    const int cloc = lane & 15;       // chunk column (= MFMA n, = A row m)
    const int q    = lane >> 4;       // quad: A/B k-group, C/D row-group

    // Zero LDS (h=0 warm-start; k=23..31 must stay zero for the padded B read).
    {
        int* hz = (int*)hbuf;
        for (int i = tid; i < (WAVES_PB * HREG) / 2; i += BLOCK) hz[i] = 0;
    }
    __syncthreads();
    _Float16* hw = hbuf + wid * HREG;
    const int hwr = cloc * KSTR;
    if (q == 0) hw[hwr + 22] = (_Float16)1.0f;   // bias row B[k=22] = 1 (own wave only)

    // ---- A fragments (VGPR-resident). Tile tt, MFMA row m: gate = m&3,
    // unit = (tt<4 ? 4*(m>>2)+tt : 16+(m>>2)); lane holds row m=cloc, k=8q+j.
    half8 af[6];
    {
        const int m = cloc;
        const int g = m & 3;
        const int u = m >> 2;
        const float scale = (g == 2) ? L2E2 : L2E;
#pragma unroll
        for (int tt = 0; tt < 5; ++tt) {
            const int unit = (tt < 4) ? (4 * u + tt) : (16 + u);
            const int R = g * 20 + unit;
#pragma unroll
            for (int j = 0; j < 8; ++j) {
                const int k = q * 8 + j;
                float val;
                if (k < 20)       val = W_hh[R * 20 + k];
                else if (k == 20) val = W_ih[R * 2 + 0];
                else if (k == 21) val = W_ih[R * 2 + 1];
                else if (k == 22) val = b_ih[R] + b_hh[R];
                else              val = 0.0f;
                af[tt][j] = (_Float16)(val * scale);
            }
        }
        // fc tile: row 0 = [fc_w(20), 0, 0, fc_b, 0...]; rows 1..15 zero. No log2e scale.
#pragma unroll
        for (int j = 0; j < 8; ++j) {
            const int k = q * 8 + j;
            float val = 0.0f;
            if (m == 0) {
                if (k < 20)       val = fc_w[k];
                else if (k == 22) val = fc_b[0];
            }
            af[5][j] = (_Float16)val;
        }
    }

    const int C = (N + CL - 1) / CL;
    const int chunk  = (blockIdx.x * WAVES_PB + wid) * 16 + cloc;
    const int gstart = chunk * CL;
    const bool live  = chunk < C;
    const bool qzero = (q == 0);

    // Only block 0 / wave 0 contains chunks with gstart < WU.
    if (blockIdx.x == 0 && wid == 0)
        scan_loop<true >(inputs, N, hw, hwr, af[0], af[1], af[2], af[3], af[4], af[5],
                         gstart, q, qzero, live, out);
    else
        scan_loop<false>(inputs, N, hw, hwr, af[0], af[1], af[2], af[3], af[4], af[5],
                         gstart, q, qzero, live, out);
}

extern "C" void kernel_launch(void* const* d_in, const int* in_sizes, int n_in,
                              void* d_out, int out_size, void* d_ws, size_t ws_size,
                              hipStream_t stream) {
    const float* inputs = (const float*)d_in[0];
    const float* cW_ih  = (const float*)d_in[1];
    const float* cW_hh  = (const float*)d_in[2];
    const float* cb_ih  = (const float*)d_in[3];
    const float* cb_hh  = (const float*)d_in[4];
    const float* cfc_w  = (const float*)d_in[5];
    const float* cfc_b  = (const float*)d_in[6];
    const float* fW_ih  = (const float*)d_in[7];
    const float* fW_hh  = (const float*)d_in[8];
    const float* fb_ih  = (const float*)d_in[9];
    const float* fb_hh  = (const float*)d_in[10];
    const float* ffc_w  = (const float*)d_in[11];
    const float* ffc_b  = (const float*)d_in[12];
    const int*   is_conv = (const int*)d_in[13];
    float* out = (float*)d_out;

    const int N = in_sizes[0];
    const int C = (N + CL - 1) / CL;                 // chunks
    const int blocks = (C + 64 - 1) / 64;            // 64 chunks per block
    lstm_mfma_kernel<<<blocks, BLOCK, 0, stream>>>(
        inputs, N, cW_ih, cW_hh, cb_ih, cb_hh, cfc_w, cfc_b,
        fW_ih, fW_hh, fb_ih, fb_hh, ffc_w, ffc_b, is_conv, out);
}

// Round 4
// 151.025 us; speedup vs baseline: 3.7515x; 1.0747x over previous
//
#include <hip/hip_runtime.h>
#include <math.h>

// LSTM learned-optimizer scan, MFMA formulation v3.
// Per wave: 16 chunks; per step one 96x32 x 32x16 f16 matmul as 6 MFMA tiles
// (5 gate tiles + 1 fc tile). Weights resident in VGPR/AGPR. h exchanged via
// per-wave LDS with KSTR=40 (80B row stride -> 2-way bank aliasing = free).
// Next-step input features are computed off the recurrence critical path.
// CL=64/WU=79: 2.25 steps/output (was 3.62).

#define CL    64            // outputs per chunk
#define WU    79            // warm-up steps (contraction kills init-state error)
#define ST    (WU + CL + 1) // 144, %4 == 0; outputs exit fc tile one step late
#define BLOCK 256
#define WAVES_PB 4
#define KSTR  40            // f16 per chunk-row (k 0..19 h, 20 lg, 21 sg, 22 bias, 23..39 zero)
#define HREG  (16 * KSTR)   // halves per wave region

typedef _Float16 half8 __attribute__((ext_vector_type(8)));
typedef _Float16 half4 __attribute__((ext_vector_type(4)));
typedef _Float16 half2 __attribute__((ext_vector_type(2)));
typedef float  float4_t __attribute__((ext_vector_type(4)));

#define L2E   1.4426950408889634f
#define L2E2  2.8853900817779268f
#define LOGSC 0.09902102579427789f   // log2(.) * ln2/7

__device__ __forceinline__ int clampi(int v, int lo, int hi) {
    return v < lo ? lo : (v > hi ? hi : v);
}

// d = [i,f,g,o] pre-scaled by log2e (g by 2*log2e).
#define ACT(dv, cv, hv) do {                                                   \
    const float ei = __builtin_amdgcn_exp2f(-(dv)[0]);                         \
    const float ef = __builtin_amdgcn_exp2f(-(dv)[1]);                         \
    const float eg = __builtin_amdgcn_exp2f(-(dv)[2]);                         \
    const float eo = __builtin_amdgcn_exp2f(-(dv)[3]);                         \
    const float f_ = __builtin_amdgcn_rcpf(1.0f + ef);                         \
    const float ig = (1.0f - eg) * __builtin_amdgcn_rcpf((1.0f + ei) * (1.0f + eg)); \
    float cn = fmaf(f_, (cv), ig);                                             \
    if (EARLY) cn *= keep;                                                     \
    (cv) = cn;                                                                 \
    const float ec = __builtin_amdgcn_exp2f(cn * -L2E2);                       \
    float hh = (1.0f - ec) * __builtin_amdgcn_rcpf((1.0f + eo) * (1.0f + ec)); \
    if (EARLY) hh *= keep;                                                     \
    (hv) = hh;                                                                 \
} while (0)

template<bool EARLY>
__device__ __forceinline__ void scan_loop(
    const float* __restrict__ inputs, int N,
    _Float16* hw, int hwr,
    half8 a0, half8 a1, half8 a2, half8 a3, half8 a4, half8 a5,
    int gstart, int q, bool qzero, bool live,
    float* __restrict__ out)
{
    float c0 = 0.f, c1 = 0.f, c2 = 0.f, c3 = 0.f, c4 = 0.f;
    const int t0 = gstart - WU;
    const float4_t zacc = {0.f, 0.f, 0.f, 0.f};

    // Features for s=0 (written by prologue caller); prefetch x for s=1.
    float xn = inputs[clampi(t0 + 1, 0, N - 1)];

    for (int su = 0; su < ST; su += 4) {
        float4_t og;
#pragma unroll
        for (int k4 = 0; k4 < 4; ++k4) {
            const int s = su + k4;

            // B fragment for step s: contiguous b128, 2-way-aliased banks (free)
            const half8 b = *(const half8*)&hw[hwr + 8 * q];

            // Features for step s+1 — independent of the recurrence chain.
            float lg = __builtin_amdgcn_logf(fabsf(xn) + 1e-7f) * LOGSC;
            lg = fmaxf(lg, -1.0f);
            const float sg = fminf(fmaxf(lg * 1096.6331584284585f, -1.0f), 1.0f);
            if (qzero) *(half2*)&hw[hwr + 20] = (half2){(_Float16)lg, (_Float16)sg};
            xn = inputs[clampi(t0 + s + 2, 0, N - 1)];

            const float4_t d0 = __builtin_amdgcn_mfma_f32_16x16x32_f16(a0, b, zacc, 0, 0, 0);
            const float4_t d1 = __builtin_amdgcn_mfma_f32_16x16x32_f16(a1, b, zacc, 0, 0, 0);
            const float4_t d2 = __builtin_amdgcn_mfma_f32_16x16x32_f16(a2, b, zacc, 0, 0, 0);
            const float4_t d3 = __builtin_amdgcn_mfma_f32_16x16x32_f16(a3, b, zacc, 0, 0, 0);
            const float4_t d4 = __builtin_amdgcn_mfma_f32_16x16x32_f16(a4, b, zacc, 0, 0, 0);
            const float4_t d5 = __builtin_amdgcn_mfma_f32_16x16x32_f16(a5, b, zacc, 0, 0, 0);

            float keep = 1.0f;
            if (EARLY) keep = (gstart + s == WU - 1) ? 0.0f : 1.0f;

            float h0, h1, h2, h3, h4;
            ACT(d0, c0, h0);
            ACT(d1, c1, h1);
            ACT(d2, c2, h2);
            ACT(d3, c3, h3);
            ACT(d4, c4, h4);

            // h for step s+1: lane owns units 4q..4q+3 (b64) and 16+q (b16)
            *(half4*)&hw[hwr + 4 * q] =
                (half4){(_Float16)h0, (_Float16)h1, (_Float16)h2, (_Float16)h3};
            hw[hwr + 16 + q] = (_Float16)h4;

            og[k4] = d5[0];   // fc . h_{s-1} + fc_b (C/D row 0 -> q==0, reg 0)
        }
        // outputs j = s-(WU+1), s = 80..143 -> group-aligned float4 stores
        if (su >= WU + 1) {
            if (qzero && live)
                *(float4_t*)(out + (gstart + su - (WU + 1))) = og;
        }
    }
}

__global__ __launch_bounds__(BLOCK, 1) void lstm_mfma_kernel(
    const float* __restrict__ inputs, int N,
    const float* __restrict__ cW_ih, const float* __restrict__ cW_hh,
    const float* __restrict__ cb_ih, const float* __restrict__ cb_hh,
    const float* __restrict__ cfc_w, const float* __restrict__ cfc_b,
    const float* __restrict__ fW_ih, const float* __restrict__ fW_hh,
    const float* __restrict__ fb_ih, const float* __restrict__ fb_hh,
    const float* __restrict__ ffc_w, const float* __restrict__ ffc_b,
    const int*   __restrict__ is_conv,
    float* __restrict__ out)
{
    __shared__ _Float16 hbuf[WAVES_PB * HREG];   // 5 KiB

    const bool conv = (is_conv[0] != 0);
    const float* W_ih = conv ? cW_ih : fW_ih;
    const float* W_hh = conv ? cW_hh : fW_hh;
    const float* b_ih = conv ? cb_ih : fb_ih;
    const float* b_hh = conv ? cb_hh : fb_hh;
    const float* fc_w = conv ? cfc_w : ffc_w;
    const float* fc_b = conv ? cfc_b : ffc_b;

    const int tid  = threadIdx.x;
    const int lane = tid & 63;
    const int wid  = tid >> 6;
    const int cloc = lane & 15;       // chunk column (= MFMA n, = A row m)
    const int q    = lane >> 4;       // quad: A/B k-group, C/D row-group

    // Zero LDS (h=0 warm-start; k=23..39 must stay zero for the padded B read).
    {
        int* hz = (int*)hbuf;
        for (int i = tid; i < (WAVES_PB * HREG) / 2; i += BLOCK) hz[i] = 0;
    }
    __syncthreads();
    _Float16* hw = hbuf + wid * HREG;
    const int hwr = cloc * KSTR;

    // ---- A fragments. Tile tt, MFMA row m: gate = m&3,
    // unit = (tt<4 ? 4*(m>>2)+tt : 16+(m>>2)); lane holds row m=cloc, k=8q+j.
    half8 af[6];
    {
        const int m = cloc;
        const int g = m & 3;
        const int u = m >> 2;
        const float scale = (g == 2) ? L2E2 : L2E;
#pragma unroll
        for (int tt = 0; tt < 5; ++tt) {
            const int unit = (tt < 4) ? (4 * u + tt) : (16 + u);
            const int R = g * 20 + unit;
#pragma unroll
            for (int j = 0; j < 8; ++j) {
                const int k = q * 8 + j;
                float val;
                if (k < 20)       val = W_hh[R * 20 + k];
                else if (k == 20) val = W_ih[R * 2 + 0];
                else if (k == 21) val = W_ih[R * 2 + 1];
                else if (k == 22) val = b_ih[R] + b_hh[R];
                else              val = 0.0f;
                af[tt][j] = (_Float16)(val * scale);
            }
        }
        // fc tile: row 0 = [fc_w(20), 0, 0, fc_b, 0...]; rows 1..15 zero. Unscaled.
#pragma unroll
        for (int j = 0; j < 8; ++j) {
            const int k = q * 8 + j;
            float val = 0.0f;
            if (m == 0) {
                if (k < 20)       val = fc_w[k];
                else if (k == 22) val = fc_b[0];
            }
            af[5][j] = (_Float16)val;
        }
    }

    const int C = (N + CL - 1) / CL;
    const int chunk  = (blockIdx.x * WAVES_PB + wid) * 16 + cloc;
    const int gstart = chunk * CL;
    const bool live  = chunk < C;
    const bool qzero = (q == 0);

    // Prologue: bias row + features for s=0.
    if (qzero) {
        const float x0 = inputs[clampi(gstart - WU, 0, N - 1)];
        float lg = __builtin_amdgcn_logf(fabsf(x0) + 1e-7f) * LOGSC;
        lg = fmaxf(lg, -1.0f);
        const float sg = fminf(fmaxf(lg * 1096.6331584284585f, -1.0f), 1.0f);
        *(half2*)&hw[hwr + 20] = (half2){(_Float16)lg, (_Float16)sg};
        hw[hwr + 22] = (_Float16)1.0f;
    }

    // Only block 0 / wave 0 contains chunks with gstart < WU.
    if (blockIdx.x == 0 && wid == 0)
        scan_loop<true >(inputs, N, hw, hwr, af[0], af[1], af[2], af[3], af[4], af[5],
                         gstart, q, qzero, live, out);
    else
        scan_loop<false>(inputs, N, hw, hwr, af[0], af[1], af[2], af[3], af[4], af[5],
                         gstart, q, qzero, live, out);
}

extern "C" void kernel_launch(void* const* d_in, const int* in_sizes, int n_in,
                              void* d_out, int out_size, void* d_ws, size_t ws_size,
                              hipStream_t stream) {
    const float* inputs = (const float*)d_in[0];
    const float* cW_ih  = (const float*)d_in[1];
    const float* cW_hh  = (const float*)d_in[2];
    const float* cb_ih  = (const float*)d_in[3];
    const float* cb_hh  = (const float*)d_in[4];
    const float* cfc_w  = (const float*)d_in[5];
    const float* cfc_b  = (const float*)d_in[6];
    const float* fW_ih  = (const float*)d_in[7];
    const float* fW_hh  = (const float*)d_in[8];
    const float* fb_ih  = (const float*)d_in[9];
    const float* fb_hh  = (const float*)d_in[10];
    const float* ffc_w  = (const float*)d_in[11];
    const float* ffc_b  = (const float*)d_in[12];
    const int*   is_conv = (const int*)d_in[13];
    float* out = (float*)d_out;

    const int N = in_sizes[0];
    const int C = (N + CL - 1) / CL;                 // chunks
    const int blocks = (C + 64 - 1) / 64;            // 64 chunks per block
    lstm_mfma_kernel<<<blocks, BLOCK, 0, stream>>>(
        inputs, N, cW_ih, cW_hh, cb_ih, cb_hh, cfc_w, cfc_b,
        fW_ih, fW_hh, fb_ih, fb_hh, ffc_w, ffc_b, is_conv, out);
}

// Round 5
// 147.321 us; speedup vs baseline: 3.8458x; 1.0251x over previous
//
#include <hip/hip_runtime.h>
#include <math.h>

// LSTM learned-optimizer scan, MFMA formulation v4.
// Per wave: 16 chunks; per step one 96x32 x 32x16 f16 matmul as 6 MFMA tiles
// (5 gate tiles + 1 fc tile). Weights VGPR-resident. h exchanged via per-wave
// LDS, KSTR=40 (80B stride -> 2-way bank aliasing = free). CL=32/WU=59 gives
// 512 blocks = 2 waves/SIMD so the per-step dependency chain (LDS round-trip
// + MFMA + activation) of one wave is filled by its sibling.

#define CL    32            // outputs per chunk
#define WU    59            // warm-up steps; (WU+1)%4==0 for output grouping
#define ST    (WU + CL + 1) // 92 steps, %4 == 0; outputs exit fc tile one step late
#define BLOCK 256
#define WAVES_PB 4
#define KSTR  40            // f16 per chunk-row (k 0..19 h, 20 lg, 21 sg, 22 bias, 23..39 zero)
#define HREG  (16 * KSTR)   // halves per wave region

typedef _Float16 half8 __attribute__((ext_vector_type(8)));
typedef _Float16 half4 __attribute__((ext_vector_type(4)));
typedef _Float16 half2 __attribute__((ext_vector_type(2)));
typedef float  float4_t __attribute__((ext_vector_type(4)));

#define L2E   1.4426950408889634f
#define L2E2  2.8853900817779268f
#define LOGSC 0.09902102579427789f   // log2(.) * ln2/7

__device__ __forceinline__ int clampi(int v, int lo, int hi) {
    return v < lo ? lo : (v > hi ? hi : v);
}

// d = [i,f,g,o] pre-scaled by log2e (g by 2*log2e).
// cn = f*c + i*g with ONE rcp: (c*pi*pg + (1-eg)*pf) / (pf*pi*pg).
#define ACT(dv, cv, hv) do {                                                   \
    const float ei = __builtin_amdgcn_exp2f(-(dv)[0]);                         \
    const float ef = __builtin_amdgcn_exp2f(-(dv)[1]);                         \
    const float eg = __builtin_amdgcn_exp2f(-(dv)[2]);                         \
    const float eo = __builtin_amdgcn_exp2f(-(dv)[3]);                         \
    const float pi_ = 1.0f + ei;                                               \
    const float pf_ = 1.0f + ef;                                               \
    const float pg_ = 1.0f + eg;                                               \
    const float pig = pi_ * pg_;                                               \
    float cn = fmaf((cv), pig, (1.0f - eg) * pf_)                              \
             * __builtin_amdgcn_rcpf(pf_ * pig);                               \
    if (EARLY) cn *= keep;                                                     \
    (cv) = cn;                                                                 \
    const float ec = __builtin_amdgcn_exp2f(cn * -L2E2);                       \
    float hh = (1.0f - ec) * __builtin_amdgcn_rcpf((1.0f + eo) * (1.0f + ec)); \
    if (EARLY) hh *= keep;                                                     \
    (hv) = hh;                                                                 \
} while (0)

template<bool EARLY>
__device__ __forceinline__ void scan_loop(
    const float* __restrict__ inputs, int N,
    _Float16* hw, int hwr,
    half8 a0, half8 a1, half8 a2, half8 a3, half8 a4, half8 a5,
    int gstart, int q, bool qzero, bool live,
    float* __restrict__ out)
{
    float c0 = 0.f, c1 = 0.f, c2 = 0.f, c3 = 0.f, c4 = 0.f;
    const int t0 = gstart - WU;
    const float4_t zacc = {0.f, 0.f, 0.f, 0.f};

    // Features for s=0 written by prologue; prefetch x for s=1.
    float xn = inputs[clampi(t0 + 1, 0, N - 1)];

    for (int su = 0; su < ST; su += 4) {
        float4_t og;
#pragma unroll
        for (int k4 = 0; k4 < 4; ++k4) {
            const int s = su + k4;

            // B fragment for step s: contiguous b128, 2-way bank aliasing (free)
            const half8 b = *(const half8*)&hw[hwr + 8 * q];

            // Features for step s+1 — independent of the recurrence chain.
            float lg = __builtin_amdgcn_logf(fabsf(xn) + 1e-7f) * LOGSC;
            lg = fmaxf(lg, -1.0f);
            const float sg = fminf(fmaxf(lg * 1096.6331584284585f, -1.0f), 1.0f);
            if (qzero) *(half2*)&hw[hwr + 20] = (half2){(_Float16)lg, (_Float16)sg};
            xn = inputs[clampi(t0 + s + 2, 0, N - 1)];

            const float4_t d0 = __builtin_amdgcn_mfma_f32_16x16x32_f16(a0, b, zacc, 0, 0, 0);
            const float4_t d1 = __builtin_amdgcn_mfma_f32_16x16x32_f16(a1, b, zacc, 0, 0, 0);
            const float4_t d2 = __builtin_amdgcn_mfma_f32_16x16x32_f16(a2, b, zacc, 0, 0, 0);
            const float4_t d3 = __builtin_amdgcn_mfma_f32_16x16x32_f16(a3, b, zacc, 0, 0, 0);
            const float4_t d4 = __builtin_amdgcn_mfma_f32_16x16x32_f16(a4, b, zacc, 0, 0, 0);
            const float4_t d5 = __builtin_amdgcn_mfma_f32_16x16x32_f16(a5, b, zacc, 0, 0, 0);

            float keep = 1.0f;
            if (EARLY) keep = (gstart + s == WU - 1) ? 0.0f : 1.0f;

            float h0, h1, h2, h3, h4;
            ACT(d0, c0, h0);
            ACT(d1, c1, h1);
            ACT(d2, c2, h2);
            ACT(d3, c3, h3);
            ACT(d4, c4, h4);

            // h for step s+1: lane owns units 4q..4q+3 (b64) and 16+q (b16)
            *(half4*)&hw[hwr + 4 * q] =
                (half4){(_Float16)h0, (_Float16)h1, (_Float16)h2, (_Float16)h3};
            hw[hwr + 16 + q] = (_Float16)h4;

            og[k4] = d5[0];   // fc . h_{s-1} + fc_b (C/D row 0 -> q==0, reg 0)
        }
        // outputs j = s-(WU+1); su = 60..88 -> 8 group-aligned float4 stores
        if (su >= WU + 1) {
            if (qzero && live)
                *(float4_t*)(out + (gstart + su - (WU + 1))) = og;
        }
    }
}

__global__ __launch_bounds__(BLOCK, 2) void lstm_mfma_kernel(
    const float* __restrict__ inputs, int N,
    const float* __restrict__ cW_ih, const float* __restrict__ cW_hh,
    const float* __restrict__ cb_ih, const float* __restrict__ cb_hh,
    const float* __restrict__ cfc_w, const float* __restrict__ cfc_b,
    const float* __restrict__ fW_ih, const float* __restrict__ fW_hh,
    const float* __restrict__ fb_ih, const float* __restrict__ fb_hh,
    const float* __restrict__ ffc_w, const float* __restrict__ ffc_b,
    const int*   __restrict__ is_conv,
    float* __restrict__ out)
{
    __shared__ _Float16 hbuf[WAVES_PB * HREG];   // 5 KiB

    const bool conv = (is_conv[0] != 0);
    const float* W_ih = conv ? cW_ih : fW_ih;
    const float* W_hh = conv ? cW_hh : fW_hh;
    const float* b_ih = conv ? cb_ih : fb_ih;
    const float* b_hh = conv ? cb_hh : fb_hh;
    const float* fc_w = conv ? cfc_w : ffc_w;
    const float* fc_b = conv ? cfc_b : ffc_b;

    const int tid  = threadIdx.x;
    const int lane = tid & 63;
    const int wid  = tid >> 6;
    const int cloc = lane & 15;       // chunk column (= MFMA n, = A row m)
    const int q    = lane >> 4;       // quad: A/B k-group, C/D row-group

    // Zero LDS (h=0 warm-start; k=23..39 must stay zero for the padded B read).
    {
        int* hz = (int*)hbuf;
        for (int i = tid; i < (WAVES_PB * HREG) / 2; i += BLOCK) hz[i] = 0;
    }
    __syncthreads();
    _Float16* hw = hbuf + wid * HREG;
    const int hwr = cloc * KSTR;

    // ---- A fragments. Tile tt, MFMA row m: gate = m&3,
    // unit = (tt<4 ? 4*(m>>2)+tt : 16+(m>>2)); lane holds row m=cloc, k=8q+j.
    half8 af[6];
    {
        const int m = cloc;
        const int g = m & 3;
        const int u = m >> 2;
        const float scale = (g == 2) ? L2E2 : L2E;
#pragma unroll
        for (int tt = 0; tt < 5; ++tt) {
            const int unit = (tt < 4) ? (4 * u + tt) : (16 + u);
            const int R = g * 20 + unit;
#pragma unroll
            for (int j = 0; j < 8; ++j) {
                const int k = q * 8 + j;
                float val;
                if (k < 20)       val = W_hh[R * 20 + k];
                else if (k == 20) val = W_ih[R * 2 + 0];
                else if (k == 21) val = W_ih[R * 2 + 1];
                else if (k == 22) val = b_ih[R] + b_hh[R];
                else              val = 0.0f;
                af[tt][j] = (_Float16)(val * scale);
            }
        }
        // fc tile: row 0 = [fc_w(20), 0, 0, fc_b, 0...]; rows 1..15 zero. Unscaled.
#pragma unroll
        for (int j = 0; j < 8; ++j) {
            const int k = q * 8 + j;
            float val = 0.0f;
            if (m == 0) {
                if (k < 20)       val = fc_w[k];
                else if (k == 22) val = fc_b[0];
            }
            af[5][j] = (_Float16)val;
        }
    }

    const int C = (N + CL - 1) / CL;
    const int chunk  = (blockIdx.x * WAVES_PB + wid) * 16 + cloc;
    const int gstart = chunk * CL;
    const bool live  = chunk < C;
    const bool qzero = (q == 0);

    // Prologue: bias row + features for s=0.
    if (qzero) {
        const float x0 = inputs[clampi(gstart - WU, 0, N - 1)];
        float lg = __builtin_amdgcn_logf(fabsf(x0) + 1e-7f) * LOGSC;
        lg = fmaxf(lg, -1.0f);
        const float sg = fminf(fmaxf(lg * 1096.6331584284585f, -1.0f), 1.0f);
        *(half2*)&hw[hwr + 20] = (half2){(_Float16)lg, (_Float16)sg};
        hw[hwr + 22] = (_Float16)1.0f;
    }

    // Only block 0 / wave 0 contains chunks with gstart < WU.
    if (blockIdx.x == 0 && wid == 0)
        scan_loop<true >(inputs, N, hw, hwr, af[0], af[1], af[2], af[3], af[4], af[5],
                         gstart, q, qzero, live, out);
    else
        scan_loop<false>(inputs, N, hw, hwr, af[0], af[1], af[2], af[3], af[4], af[5],
                         gstart, q, qzero, live, out);
}

extern "C" void kernel_launch(void* const* d_in, const int* in_sizes, int n_in,
                              void* d_out, int out_size, void* d_ws, size_t ws_size,
                              hipStream_t stream) {
    const float* inputs = (const float*)d_in[0];
    const float* cW_ih  = (const float*)d_in[1];
    const float* cW_hh  = (const float*)d_in[2];
    const float* cb_ih  = (const float*)d_in[3];
    const float* cb_hh  = (const float*)d_in[4];
    const float* cfc_w  = (const float*)d_in[5];
    const float* cfc_b  = (const float*)d_in[6];
    const float* fW_ih  = (const float*)d_in[7];
    const float* fW_hh  = (const float*)d_in[8];
    const float* fb_ih  = (const float*)d_in[9];
    const float* fb_hh  = (const float*)d_in[10];
    const float* ffc_w  = (const float*)d_in[11];
    const float* ffc_b  = (const float*)d_in[12];
    const int*   is_conv = (const int*)d_in[13];
    float* out = (float*)d_out;

    const int N = in_sizes[0];
    const int C = (N + CL - 1) / CL;                 // chunks (32768)
    const int blocks = (C + 64 - 1) / 64;            // 64 chunks per block -> 512
    lstm_mfma_kernel<<<blocks, BLOCK, 0, stream>>>(
        inputs, N, cW_ih, cW_hh, cb_ih, cb_hh, cfc_w, cfc_b,
        fW_ih, fW_hh, fb_ih, fb_hh, ffc_w, ffc_b, is_conv, out);
}

// Round 7
// 135.694 us; speedup vs baseline: 4.1754x; 1.0857x over previous
//
#include <hip/hip_runtime.h>
#include <math.h>

// LSTM learned-optimizer scan, MFMA formulation v5 — shuffle-free.
// Per wave: 16 chunks; per step one 96x32 x 32x16 f16 matmul (5 gate tiles +
// 1 fc tile). The k-dimension is permuted so slots k=8q..8q+7 are exactly the
// features lane (cloc,q) computes itself: units {4q..4q+3, 16+q} + (lg,sg,1)
// in q==0's spare slots. B is assembled from the lane's OWN registers via
// v_cvt_pkrtz — no LDS, no shuffles, no barriers in the recurrence.
// Recurrence chain: MFMA -> ACT -> cvt_pk -> MFMA.

#define CL    32            // outputs per chunk
#define WU    59            // warm-up steps; (WU+1)%4==0 for output grouping
#define ST    (WU + CL + 1) // 92 steps; outputs exit fc tile one step late
#define BLOCK 256
#define WAVES_PB 4

typedef _Float16 half8 __attribute__((ext_vector_type(8)));
typedef __fp16   fp16x2 __attribute__((ext_vector_type(2)));   // cvt_pkrtz return type
typedef float  float4_t __attribute__((ext_vector_type(4)));

union B8 { half8 v; fp16x2 p[4]; };

#define L2E   1.4426950408889634f
#define L2E2  2.8853900817779268f
#define LOGSC 0.09902102579427789f   // log2(.) * ln2/7

__device__ __forceinline__ int clampi(int v, int lo, int hi) {
    return v < lo ? lo : (v > hi ? hi : v);
}

// d = [i,f,g,o] pre-scaled by log2e (g by 2*log2e).
// cn = f*c + i*g with one rcp: (c*pi*pg + (1-eg)*pf) * rcp(pf*pi*pg).
#define ACT(dv, cv, hv) do {                                                   \
    const float ei = __builtin_amdgcn_exp2f(-(dv)[0]);                         \
    const float ef = __builtin_amdgcn_exp2f(-(dv)[1]);                         \
    const float eg = __builtin_amdgcn_exp2f(-(dv)[2]);                         \
    const float eo = __builtin_amdgcn_exp2f(-(dv)[3]);                         \
    const float pi_ = 1.0f + ei;                                               \
    const float pf_ = 1.0f + ef;                                               \
    const float pg_ = 1.0f + eg;                                               \
    const float pig = pi_ * pg_;                                               \
    float cn = fmaf((cv), pig, (1.0f - eg) * pf_)                              \
             * __builtin_amdgcn_rcpf(pf_ * pig);                               \
    if (EARLY) cn *= keep;                                                     \
    (cv) = cn;                                                                 \
    const float ec = __builtin_amdgcn_exp2f(cn * -L2E2);                       \
    float hh = (1.0f - ec) * __builtin_amdgcn_rcpf((1.0f + eo) * (1.0f + ec)); \
    if (EARLY) hh *= keep;                                                     \
    (hv) = hh;                                                                 \
} while (0)

template<bool EARLY, bool CLAMP>
__device__ __forceinline__ void scan_loop(
    const float* __restrict__ inputs, int N,
    half8 a0, half8 a1, half8 a2, half8 a3, half8 a4, half8 a5,
    int gstart, bool qzero, bool live,
    float* __restrict__ out)
{
    float c0 = 0.f, c1 = 0.f, c2 = 0.f, c3 = 0.f, c4 = 0.f;
    const int t0 = gstart - WU;
    const float4_t zacc = {0.f, 0.f, 0.f, 0.f};
    const float onq = qzero ? 1.0f : 0.0f;

    // s=0 features (h = 0).
    float xc = inputs[CLAMP ? clampi(t0, 0, N - 1) : t0];
    float lg0 = fmaxf(__builtin_amdgcn_logf(fabsf(xc) + 1e-7f) * LOGSC, -1.0f);
    float sg0 = fminf(fmaxf(lg0 * 1096.6331584284585f, -1.0f), 1.0f);
    B8 bb;
    bb.p[0] = __builtin_amdgcn_cvt_pkrtz(0.f, 0.f);
    bb.p[1] = __builtin_amdgcn_cvt_pkrtz(0.f, 0.f);
    bb.p[2] = __builtin_amdgcn_cvt_pkrtz(0.f, qzero ? lg0 : 0.f);
    bb.p[3] = __builtin_amdgcn_cvt_pkrtz(qzero ? sg0 : 0.f, onq);
    float xn = inputs[CLAMP ? clampi(t0 + 1, 0, N - 1) : (t0 + 1)];

    for (int su = 0; su < ST; su += 4) {
        float4_t og;
#pragma unroll
        for (int k4 = 0; k4 < 4; ++k4) {
            const int s = su + k4;
            const half8 b = bb.v;

            // Features for s+1 — off the recurrence chain.
            float lg = fmaxf(__builtin_amdgcn_logf(fabsf(xn) + 1e-7f) * LOGSC, -1.0f);
            const float sg = fminf(fmaxf(lg * 1096.6331584284585f, -1.0f), 1.0f);
            xn = inputs[CLAMP ? clampi(t0 + s + 2, 0, N - 1) : (t0 + s + 2)];

            const float4_t d0 = __builtin_amdgcn_mfma_f32_16x16x32_f16(a0, b, zacc, 0, 0, 0);
            const float4_t d1 = __builtin_amdgcn_mfma_f32_16x16x32_f16(a1, b, zacc, 0, 0, 0);
            const float4_t d2 = __builtin_amdgcn_mfma_f32_16x16x32_f16(a2, b, zacc, 0, 0, 0);
            const float4_t d3 = __builtin_amdgcn_mfma_f32_16x16x32_f16(a3, b, zacc, 0, 0, 0);
            const float4_t d4 = __builtin_amdgcn_mfma_f32_16x16x32_f16(a4, b, zacc, 0, 0, 0);
            const float4_t d5 = __builtin_amdgcn_mfma_f32_16x16x32_f16(a5, b, zacc, 0, 0, 0);

            float keep = 1.0f;
            if (EARLY) keep = (gstart + s == WU - 1) ? 0.0f : 1.0f;

            float h0, h1, h2, h3, h4;
            ACT(d0, c0, h0);
            ACT(d1, c1, h1);
            ACT(d2, c2, h2);
            ACT(d3, c3, h3);
            ACT(d4, c4, h4);

            // Rebuild B from own registers (units 4q..4q+3, 16+q, then lg/sg/1).
            bb.p[0] = __builtin_amdgcn_cvt_pkrtz(h0, h1);
            bb.p[1] = __builtin_amdgcn_cvt_pkrtz(h2, h3);
            bb.p[2] = __builtin_amdgcn_cvt_pkrtz(h4, qzero ? lg : 0.f);
            bb.p[3] = __builtin_amdgcn_cvt_pkrtz(qzero ? sg : 0.f, onq);

            og[k4] = d5[0];   // fc . h_{s-1} + fc_b (C/D row 0 -> q==0, reg 0)
        }
        // outputs j = s-(WU+1); su = 60..88 -> 8 group-aligned float4 stores
        if (su >= WU + 1) {
            if (qzero && live)
                *(float4_t*)(out + (gstart + su - (WU + 1))) = og;
        }
    }
}

__global__ __launch_bounds__(BLOCK, 2) void lstm_mfma_kernel(
    const float* __restrict__ inputs, int N,
    const float* __restrict__ cW_ih, const float* __restrict__ cW_hh,
    const float* __restrict__ cb_ih, const float* __restrict__ cb_hh,
    const float* __restrict__ cfc_w, const float* __restrict__ cfc_b,
    const float* __restrict__ fW_ih, const float* __restrict__ fW_hh,
    const float* __restrict__ fb_ih, const float* __restrict__ fb_hh,
    const float* __restrict__ ffc_w, const float* __restrict__ ffc_b,
    const int*   __restrict__ is_conv,
    float* __restrict__ out)
{
    const bool conv = (is_conv[0] != 0);
    const float* W_ih = conv ? cW_ih : fW_ih;
    const float* W_hh = conv ? cW_hh : fW_hh;
    const float* b_ih = conv ? cb_ih : fb_ih;
    const float* b_hh = conv ? cb_hh : fb_hh;
    const float* fc_w = conv ? cfc_w : ffc_w;
    const float* fc_b = conv ? cfc_b : ffc_b;

    const int tid  = threadIdx.x;
    const int lane = tid & 63;
    const int wid  = tid >> 6;
    const int cloc = lane & 15;       // chunk column (= MFMA n, = A row m)
    const int q    = lane >> 4;       // quad: A/B k-group, C/D row-group

    // ---- A fragments (VGPR-resident), k-permuted.
    // Row m of tile tt: gate g = m&3, unit = (tt<4 ? 4*(m>>2)+tt : 16+(m>>2)).
    // Column k = 8q+j holds feature: j<4 -> h-unit 4q+j; j==4 -> h-unit 16+q;
    // j==5 -> lg (q==0 only); j==6 -> sg (q==0); j==7 -> bias (q==0).
    half8 af[6];
    {
        const int m = cloc;
        const int g = m & 3;
        const int u = m >> 2;
        const float scale = (g == 2) ? L2E2 : L2E;
#pragma unroll
        for (int tt = 0; tt < 5; ++tt) {
            const int unit = (tt < 4) ? (4 * u + tt) : (16 + u);
            const int R = g * 20 + unit;
#pragma unroll
            for (int j = 0; j < 8; ++j) {
                float val = 0.0f;
                if (j < 4)        val = W_hh[R * 20 + (4 * q + j)];
                else if (j == 4)  val = W_hh[R * 20 + (16 + q)];
                else if (q == 0) {
                    if (j == 5)      val = W_ih[R * 2 + 0];
                    else if (j == 6) val = W_ih[R * 2 + 1];
                    else             val = b_ih[R] + b_hh[R];
                }
                af[tt][j] = (_Float16)(val * scale);
            }
        }
        // fc tile: row 0 = fc weights in the same k-permutation; rows 1..15 zero.
#pragma unroll
        for (int j = 0; j < 8; ++j) {
            float val = 0.0f;
            if (m == 0) {
                if (j < 4)                 val = fc_w[4 * q + j];
                else if (j == 4)           val = fc_w[16 + q];
                else if (j == 7 && q == 0) val = fc_b[0];
            }
            af[5][j] = (_Float16)val;
        }
    }

    const int C = (N + CL - 1) / CL;
    const int chunk  = (blockIdx.x * WAVES_PB + wid) * 16 + cloc;
    const int gstart = chunk * CL;
    const bool live  = chunk < C;
    const bool qzero = (q == 0);

    const int bid = blockIdx.x, lastb = gridDim.x - 1;
    if (bid == 0) {
        if (wid == 0)
            scan_loop<true , true >(inputs, N, af[0], af[1], af[2], af[3], af[4], af[5],
                                    gstart, qzero, live, out);
        else
            scan_loop<false, true >(inputs, N, af[0], af[1], af[2], af[3], af[4], af[5],
                                    gstart, qzero, live, out);
    } else if (bid == lastb) {
        scan_loop<false, true >(inputs, N, af[0], af[1], af[2], af[3], af[4], af[5],
                                gstart, qzero, live, out);
    } else {
        scan_loop<false, false>(inputs, N, af[0], af[1], af[2], af[3], af[4], af[5],
                                gstart, qzero, live, out);
    }
}

extern "C" void kernel_launch(void* const* d_in, const int* in_sizes, int n_in,
                              void* d_out, int out_size, void* d_ws, size_t ws_size,
                              hipStream_t stream) {
    const float* inputs = (const float*)d_in[0];
    const float* cW_ih  = (const float*)d_in[1];
    const float* cW_hh  = (const float*)d_in[2];
    const float* cb_ih  = (const float*)d_in[3];
    const float* cb_hh  = (const float*)d_in[4];
    const float* cfc_w  = (const float*)d_in[5];
    const float* cfc_b  = (const float*)d_in[6];
    const float* fW_ih  = (const float*)d_in[7];
    const float* fW_hh  = (const float*)d_in[8];
    const float* fb_ih  = (const float*)d_in[9];
    const float* fb_hh  = (const float*)d_in[10];
    const float* ffc_w  = (const float*)d_in[11];
    const float* ffc_b  = (const float*)d_in[12];
    const int*   is_conv = (const int*)d_in[13];
    float* out = (float*)d_out;

    const int N = in_sizes[0];
    const int C = (N + CL - 1) / CL;                 // chunks (32768 at N=1M)
    const int blocks = (C + 64 - 1) / 64;            // 64 chunks per block -> 512
    lstm_mfma_kernel<<<blocks, BLOCK, 0, stream>>>(
        inputs, N, cW_ih, cW_hh, cb_ih, cb_hh, cfc_w, cfc_b,
        fW_ih, fW_hh, fb_ih, fb_hh, ffc_w, ffc_b, is_conv, out);
}

// Round 8
// 126.460 us; speedup vs baseline: 4.4802x; 1.0730x over previous
//
#include <hip/hip_runtime.h>
#include <math.h>

// LSTM learned-optimizer scan, MFMA formulation v6 — shuffle-free, WU=43.
// Per wave: 16 chunks; per step one 96x32 x 32x16 f16 matmul (5 gate tiles +
// 1 fc tile). k-dimension permuted so slots k=8q..8q+7 are exactly the
// features lane (cloc,q) computes itself: units {4q..4q+3, 16+q} + (lg,sg,1)
// in q==0's spare slots. B is assembled from the lane's OWN registers via
// v_cvt_pkrtz — no LDS, no shuffles, no barriers in the recurrence.
// Recurrence chain: MFMA -> ACT -> cvt_pk -> MFMA.
// WU=43: absmax was bit-identical (f16-weight floor) from WU=96..59, so
// warm-up truncation is far below the 6.25e-3 threshold; ST 92->76 = -17%.

#define CL    32            // outputs per chunk
#define WU    43            // warm-up steps; (WU+1)%4==0 for output grouping
#define ST    (WU + CL + 1) // 76 steps; outputs exit fc tile one step late
#define BLOCK 256
#define WAVES_PB 4

typedef _Float16 half8 __attribute__((ext_vector_type(8)));
typedef __fp16   fp16x2 __attribute__((ext_vector_type(2)));   // cvt_pkrtz return type
typedef float  float4_t __attribute__((ext_vector_type(4)));

union B8 { half8 v; fp16x2 p[4]; };

#define L2E   1.4426950408889634f
#define L2E2  2.8853900817779268f
#define LOGSC 0.09902102579427789f   // log2(.) * ln2/7

__device__ __forceinline__ int clampi(int v, int lo, int hi) {
    return v < lo ? lo : (v > hi ? hi : v);
}

// d = [i,f,g,o] pre-scaled by log2e (g by 2*log2e).
// cn = f*c + i*g with one rcp: (c*pi*pg + (1-eg)*pf) * rcp(pf*pi*pg).
#define ACT(dv, cv, hv) do {                                                   \
    const float ei = __builtin_amdgcn_exp2f(-(dv)[0]);                         \
    const float ef = __builtin_amdgcn_exp2f(-(dv)[1]);                         \
    const float eg = __builtin_amdgcn_exp2f(-(dv)[2]);                         \
    const float eo = __builtin_amdgcn_exp2f(-(dv)[3]);                         \
    const float pi_ = 1.0f + ei;                                               \
    const float pf_ = 1.0f + ef;                                               \
    const float pg_ = 1.0f + eg;                                               \
    const float pig = pi_ * pg_;                                               \
    float cn = fmaf((cv), pig, (1.0f - eg) * pf_)                              \
             * __builtin_amdgcn_rcpf(pf_ * pig);                               \
    if (EARLY) cn *= keep;                                                     \
    (cv) = cn;                                                                 \
    const float ec = __builtin_amdgcn_exp2f(cn * -L2E2);                       \
    float hh = (1.0f - ec) * __builtin_amdgcn_rcpf((1.0f + eo) * (1.0f + ec)); \
    if (EARLY) hh *= keep;                                                     \
    (hv) = hh;                                                                 \
} while (0)

template<bool EARLY, bool CLAMP>
__device__ __forceinline__ void scan_loop(
    const float* __restrict__ inputs, int N,
    half8 a0, half8 a1, half8 a2, half8 a3, half8 a4, half8 a5,
    int gstart, bool qzero, bool live,
    float* __restrict__ out)
{
    float c0 = 0.f, c1 = 0.f, c2 = 0.f, c3 = 0.f, c4 = 0.f;
    const int t0 = gstart - WU;
    const float4_t zacc = {0.f, 0.f, 0.f, 0.f};
    const float onq = qzero ? 1.0f : 0.0f;

    // s=0 features (h = 0).
    float xc = inputs[CLAMP ? clampi(t0, 0, N - 1) : t0];
    float lg0 = fmaxf(__builtin_amdgcn_logf(fabsf(xc) + 1e-7f) * LOGSC, -1.0f);
    float sg0 = fminf(fmaxf(lg0 * 1096.6331584284585f, -1.0f), 1.0f);
    B8 bb;
    bb.p[0] = __builtin_amdgcn_cvt_pkrtz(0.f, 0.f);
    bb.p[1] = __builtin_amdgcn_cvt_pkrtz(0.f, 0.f);
    bb.p[2] = __builtin_amdgcn_cvt_pkrtz(0.f, qzero ? lg0 : 0.f);
    bb.p[3] = __builtin_amdgcn_cvt_pkrtz(qzero ? sg0 : 0.f, onq);
    float xn = inputs[CLAMP ? clampi(t0 + 1, 0, N - 1) : (t0 + 1)];

    for (int su = 0; su < ST; su += 4) {
        float4_t og;
#pragma unroll
        for (int k4 = 0; k4 < 4; ++k4) {
            const int s = su + k4;
            const half8 b = bb.v;

            // Features for s+1 — off the recurrence chain.
            float lg = fmaxf(__builtin_amdgcn_logf(fabsf(xn) + 1e-7f) * LOGSC, -1.0f);
            const float sg = fminf(fmaxf(lg * 1096.6331584284585f, -1.0f), 1.0f);
            xn = inputs[CLAMP ? clampi(t0 + s + 2, 0, N - 1) : (t0 + s + 2)];

            const float4_t d0 = __builtin_amdgcn_mfma_f32_16x16x32_f16(a0, b, zacc, 0, 0, 0);
            const float4_t d1 = __builtin_amdgcn_mfma_f32_16x16x32_f16(a1, b, zacc, 0, 0, 0);
            const float4_t d2 = __builtin_amdgcn_mfma_f32_16x16x32_f16(a2, b, zacc, 0, 0, 0);
            const float4_t d3 = __builtin_amdgcn_mfma_f32_16x16x32_f16(a3, b, zacc, 0, 0, 0);
            const float4_t d4 = __builtin_amdgcn_mfma_f32_16x16x32_f16(a4, b, zacc, 0, 0, 0);
            const float4_t d5 = __builtin_amdgcn_mfma_f32_16x16x32_f16(a5, b, zacc, 0, 0, 0);

            float keep = 1.0f;
            if (EARLY) keep = (gstart + s == WU - 1) ? 0.0f : 1.0f;

            float h0, h1, h2, h3, h4;
            ACT(d0, c0, h0);
            ACT(d1, c1, h1);
            ACT(d2, c2, h2);
            ACT(d3, c3, h3);
            ACT(d4, c4, h4);

            // Rebuild B from own registers (units 4q..4q+3, 16+q, then lg/sg/1).
            bb.p[0] = __builtin_amdgcn_cvt_pkrtz(h0, h1);
            bb.p[1] = __builtin_amdgcn_cvt_pkrtz(h2, h3);
            bb.p[2] = __builtin_amdgcn_cvt_pkrtz(h4, qzero ? lg : 0.f);
            bb.p[3] = __builtin_amdgcn_cvt_pkrtz(qzero ? sg : 0.f, onq);

            og[k4] = d5[0];   // fc . h_{s-1} + fc_b (C/D row 0 -> q==0, reg 0)
        }
        // outputs j = s-(WU+1); su = 44..72 -> 8 group-aligned float4 stores
        if (su >= WU + 1) {
            if (qzero && live)
                *(float4_t*)(out + (gstart + su - (WU + 1))) = og;
        }
    }
}

__global__ __launch_bounds__(BLOCK, 2) void lstm_mfma_kernel(
    const float* __restrict__ inputs, int N,
    const float* __restrict__ cW_ih, const float* __restrict__ cW_hh,
    const float* __restrict__ cb_ih, const float* __restrict__ cb_hh,
    const float* __restrict__ cfc_w, const float* __restrict__ cfc_b,
    const float* __restrict__ fW_ih, const float* __restrict__ fW_hh,
    const float* __restrict__ fb_ih, const float* __restrict__ fb_hh,
    const float* __restrict__ ffc_w, const float* __restrict__ ffc_b,
    const int*   __restrict__ is_conv,
    float* __restrict__ out)
{
    const bool conv = (is_conv[0] != 0);
    const float* W_ih = conv ? cW_ih : fW_ih;
    const float* W_hh = conv ? cW_hh : fW_hh;
    const float* b_ih = conv ? cb_ih : fb_ih;
    const float* b_hh = conv ? cb_hh : fb_hh;
    const float* fc_w = conv ? cfc_w : ffc_w;
    const float* fc_b = conv ? cfc_b : ffc_b;

    const int tid  = threadIdx.x;
    const int lane = tid & 63;
    const int wid  = tid >> 6;
    const int cloc = lane & 15;       // chunk column (= MFMA n, = A row m)
    const int q    = lane >> 4;       // quad: A/B k-group, C/D row-group

    // ---- A fragments (VGPR-resident), k-permuted.
    // Row m of tile tt: gate g = m&3, unit = (tt<4 ? 4*(m>>2)+tt : 16+(m>>2)).
    // Column k = 8q+j holds feature: j<4 -> h-unit 4q+j; j==4 -> h-unit 16+q;
    // j==5 -> lg (q==0 only); j==6 -> sg (q==0); j==7 -> bias (q==0).
    half8 af[6];
    {
        const int m = cloc;
        const int g = m & 3;
        const int u = m >> 2;
        const float scale = (g == 2) ? L2E2 : L2E;
#pragma unroll
        for (int tt = 0; tt < 5; ++tt) {
            const int unit = (tt < 4) ? (4 * u + tt) : (16 + u);
            const int R = g * 20 + unit;
#pragma unroll
            for (int j = 0; j < 8; ++j) {
                float val = 0.0f;
                if (j < 4)        val = W_hh[R * 20 + (4 * q + j)];
                else if (j == 4)  val = W_hh[R * 20 + (16 + q)];
                else if (q == 0) {
                    if (j == 5)      val = W_ih[R * 2 + 0];
                    else if (j == 6) val = W_ih[R * 2 + 1];
                    else             val = b_ih[R] + b_hh[R];
                }
                af[tt][j] = (_Float16)(val * scale);
            }
        }
        // fc tile: row 0 = fc weights in the same k-permutation; rows 1..15 zero.
#pragma unroll
        for (int j = 0; j < 8; ++j) {
            float val = 0.0f;
            if (m == 0) {
                if (j < 4)                 val = fc_w[4 * q + j];
                else if (j == 4)           val = fc_w[16 + q];
                else if (j == 7 && q == 0) val = fc_b[0];
            }
            af[5][j] = (_Float16)val;
        }
    }

    const int C = (N + CL - 1) / CL;
    const int chunk  = (blockIdx.x * WAVES_PB + wid) * 16 + cloc;
    const int gstart = chunk * CL;
    const bool live  = chunk < C;
    const bool qzero = (q == 0);

    const int bid = blockIdx.x, lastb = gridDim.x - 1;
    if (bid == 0) {
        if (wid == 0)
            scan_loop<true , true >(inputs, N, af[0], af[1], af[2], af[3], af[4], af[5],
                                    gstart, qzero, live, out);
        else
            scan_loop<false, true >(inputs, N, af[0], af[1], af[2], af[3], af[4], af[5],
                                    gstart, qzero, live, out);
    } else if (bid == lastb) {
        scan_loop<false, true >(inputs, N, af[0], af[1], af[2], af[3], af[4], af[5],
                                gstart, qzero, live, out);
    } else {
        scan_loop<false, false>(inputs, N, af[0], af[1], af[2], af[3], af[4], af[5],
                                gstart, qzero, live, out);
    }
}

extern "C" void kernel_launch(void* const* d_in, const int* in_sizes, int n_in,
                              void* d_out, int out_size, void* d_ws, size_t ws_size,
                              hipStream_t stream) {
    const float* inputs = (const float*)d_in[0];
    const float* cW_ih  = (const float*)d_in[1];
    const float* cW_hh  = (const float*)d_in[2];
    const float* cb_ih  = (const float*)d_in[3];
    const float* cb_hh  = (const float*)d_in[4];
    const float* cfc_w  = (const float*)d_in[5];
    const float* cfc_b  = (const float*)d_in[6];
    const float* fW_ih  = (const float*)d_in[7];
    const float* fW_hh  = (const float*)d_in[8];
    const float* fb_ih  = (const float*)d_in[9];
    const float* fb_hh  = (const float*)d_in[10];
    const float* ffc_w  = (const float*)d_in[11];
    const float* ffc_b  = (const float*)d_in[12];
    const int*   is_conv = (const int*)d_in[13];
    float* out = (float*)d_out;

    const int N = in_sizes[0];
    const int C = (N + CL - 1) / CL;                 // chunks (32768 at N=1M)
    const int blocks = (C + 64 - 1) / 64;            // 64 chunks per block -> 512
    lstm_mfma_kernel<<<blocks, BLOCK, 0, stream>>>(
        inputs, N, cW_ih, cW_hh, cb_ih, cb_hh, cfc_w, cfc_b,
        fW_ih, fW_hh, fb_ih, fb_hh, ffc_w, ffc_b, is_conv, out);
}

// Round 9
// 118.024 us; speedup vs baseline: 4.8005x; 1.0715x over previous
//
#include <hip/hip_runtime.h>
#include <math.h>

// LSTM learned-optimizer scan, MFMA formulation v7 — shuffle-free, WU=27.
// Per wave: 16 chunks; per step one 96x32 x 32x16 f16 matmul (5 gate tiles +
// 1 fc tile). k-dimension permuted so slots k=8q..8q+7 are exactly the
// features lane (cloc,q) computes itself: units {4q..4q+3, 16+q} + (lg,sg,1)
// in q==0's spare slots. B is assembled from the lane's OWN registers via
// v_cvt_pkrtz — no LDS, no shuffles, no barriers in the recurrence.
// Recurrence chain: MFMA -> ACT -> cvt_pk -> MFMA.
// WU history: 96/59/43 all bit-identical absmax (f16-weight floor 1.95e-3),
// so warm-up truncation has slack; WU=27 keeps worst-case ~1.6e-3 vs 6.25e-3.

#define CL    32            // outputs per chunk
#define WU    27            // warm-up steps; (WU+1)%4==0 for output grouping
#define ST    (WU + CL + 1) // 60 steps; outputs exit fc tile one step late
#define BLOCK 256
#define WAVES_PB 4

typedef _Float16 half8 __attribute__((ext_vector_type(8)));
typedef __fp16   fp16x2 __attribute__((ext_vector_type(2)));   // cvt_pkrtz return type
typedef float  float4_t __attribute__((ext_vector_type(4)));

union B8 { half8 v; fp16x2 p[4]; };

#define L2E   1.4426950408889634f
#define L2E2  2.8853900817779268f
#define LOGSC 0.09902102579427789f   // log2(.) * ln2/7

__device__ __forceinline__ int clampi(int v, int lo, int hi) {
    return v < lo ? lo : (v > hi ? hi : v);
}

// d = [i,f,g,o] pre-scaled by log2e (g by 2*log2e).
// cn = f*c + i*g with one rcp: (c*pi*pg + (1-eg)*pf) * rcp(pf*pi*pg).
#define ACT(dv, cv, hv) do {                                                   \
    const float ei = __builtin_amdgcn_exp2f(-(dv)[0]);                         \
    const float ef = __builtin_amdgcn_exp2f(-(dv)[1]);                         \
    const float eg = __builtin_amdgcn_exp2f(-(dv)[2]);                         \
    const float eo = __builtin_amdgcn_exp2f(-(dv)[3]);                         \
    const float pi_ = 1.0f + ei;                                               \
    const float pf_ = 1.0f + ef;                                               \
    const float pg_ = 1.0f + eg;                                               \
    const float pig = pi_ * pg_;                                               \
    float cn = fmaf((cv), pig, (1.0f - eg) * pf_)                              \
             * __builtin_amdgcn_rcpf(pf_ * pig);                               \
    if (EARLY) cn *= keep;                                                     \
    (cv) = cn;                                                                 \
    const float ec = __builtin_amdgcn_exp2f(cn * -L2E2);                       \
    float hh = (1.0f - ec) * __builtin_amdgcn_rcpf((1.0f + eo) * (1.0f + ec)); \
    if (EARLY) hh *= keep;                                                     \
    (hv) = hh;                                                                 \
} while (0)

template<bool EARLY, bool CLAMP>
__device__ __forceinline__ void scan_loop(
    const float* __restrict__ inputs, int N,
    half8 a0, half8 a1, half8 a2, half8 a3, half8 a4, half8 a5,
    int gstart, bool qzero, bool live,
    float* __restrict__ out)
{
    float c0 = 0.f, c1 = 0.f, c2 = 0.f, c3 = 0.f, c4 = 0.f;
    const int t0 = gstart - WU;
    const float4_t zacc = {0.f, 0.f, 0.f, 0.f};
    const float onq = qzero ? 1.0f : 0.0f;

    // s=0 features (h = 0).
    float xc = inputs[CLAMP ? clampi(t0, 0, N - 1) : t0];
    float lg0 = fmaxf(__builtin_amdgcn_logf(fabsf(xc) + 1e-7f) * LOGSC, -1.0f);
    float sg0 = fminf(fmaxf(lg0 * 1096.6331584284585f, -1.0f), 1.0f);
    B8 bb;
    bb.p[0] = __builtin_amdgcn_cvt_pkrtz(0.f, 0.f);
    bb.p[1] = __builtin_amdgcn_cvt_pkrtz(0.f, 0.f);
    bb.p[2] = __builtin_amdgcn_cvt_pkrtz(0.f, qzero ? lg0 : 0.f);
    bb.p[3] = __builtin_amdgcn_cvt_pkrtz(qzero ? sg0 : 0.f, onq);
    float xn = inputs[CLAMP ? clampi(t0 + 1, 0, N - 1) : (t0 + 1)];

    for (int su = 0; su < ST; su += 4) {
        float4_t og;
#pragma unroll
        for (int k4 = 0; k4 < 4; ++k4) {
            const int s = su + k4;
            const half8 b = bb.v;

            // Features for s+1 — off the recurrence chain.
            float lg = fmaxf(__builtin_amdgcn_logf(fabsf(xn) + 1e-7f) * LOGSC, -1.0f);
            const float sg = fminf(fmaxf(lg * 1096.6331584284585f, -1.0f), 1.0f);
            xn = inputs[CLAMP ? clampi(t0 + s + 2, 0, N - 1) : (t0 + s + 2)];

            const float4_t d0 = __builtin_amdgcn_mfma_f32_16x16x32_f16(a0, b, zacc, 0, 0, 0);
            const float4_t d1 = __builtin_amdgcn_mfma_f32_16x16x32_f16(a1, b, zacc, 0, 0, 0);
            const float4_t d2 = __builtin_amdgcn_mfma_f32_16x16x32_f16(a2, b, zacc, 0, 0, 0);
            const float4_t d3 = __builtin_amdgcn_mfma_f32_16x16x32_f16(a3, b, zacc, 0, 0, 0);
            const float4_t d4 = __builtin_amdgcn_mfma_f32_16x16x32_f16(a4, b, zacc, 0, 0, 0);
            const float4_t d5 = __builtin_amdgcn_mfma_f32_16x16x32_f16(a5, b, zacc, 0, 0, 0);

            float keep = 1.0f;
            if (EARLY) keep = (gstart + s == WU - 1) ? 0.0f : 1.0f;

            float h0, h1, h2, h3, h4;
            ACT(d0, c0, h0);
            ACT(d1, c1, h1);
            ACT(d2, c2, h2);
            ACT(d3, c3, h3);
            ACT(d4, c4, h4);

            // Rebuild B from own registers (units 4q..4q+3, 16+q, then lg/sg/1).
            bb.p[0] = __builtin_amdgcn_cvt_pkrtz(h0, h1);
            bb.p[1] = __builtin_amdgcn_cvt_pkrtz(h2, h3);
            bb.p[2] = __builtin_amdgcn_cvt_pkrtz(h4, qzero ? lg : 0.f);
            bb.p[3] = __builtin_amdgcn_cvt_pkrtz(qzero ? sg : 0.f, onq);

            og[k4] = d5[0];   // fc . h_{s-1} + fc_b (C/D row 0 -> q==0, reg 0)
        }
        // outputs j = s-(WU+1); su = 28..56 -> 8 group-aligned float4 stores
        if (su >= WU + 1) {
            if (qzero && live)
                *(float4_t*)(out + (gstart + su - (WU + 1))) = og;
        }
    }
}

__global__ __launch_bounds__(BLOCK, 2) void lstm_mfma_kernel(
    const float* __restrict__ inputs, int N,
    const float* __restrict__ cW_ih, const float* __restrict__ cW_hh,
    const float* __restrict__ cb_ih, const float* __restrict__ cb_hh,
    const float* __restrict__ cfc_w, const float* __restrict__ cfc_b,
    const float* __restrict__ fW_ih, const float* __restrict__ fW_hh,
    const float* __restrict__ fb_ih, const float* __restrict__ fb_hh,
    const float* __restrict__ ffc_w, const float* __restrict__ ffc_b,
    const int*   __restrict__ is_conv,
    float* __restrict__ out)
{
    const bool conv = (is_conv[0] != 0);
    const float* W_ih = conv ? cW_ih : fW_ih;
    const float* W_hh = conv ? cW_hh : fW_hh;
    const float* b_ih = conv ? cb_ih : fb_ih;
    const float* b_hh = conv ? cb_hh : fb_hh;
    const float* fc_w = conv ? cfc_w : ffc_w;
    const float* fc_b = conv ? cfc_b : ffc_b;

    const int tid  = threadIdx.x;
    const int lane = tid & 63;
    const int wid  = tid >> 6;
    const int cloc = lane & 15;       // chunk column (= MFMA n, = A row m)
    const int q    = lane >> 4;       // quad: A/B k-group, C/D row-group

    // ---- A fragments (VGPR-resident), k-permuted.
    // Row m of tile tt: gate g = m&3, unit = (tt<4 ? 4*(m>>2)+tt : 16+(m>>2)).
    // Column k = 8q+j holds feature: j<4 -> h-unit 4q+j; j==4 -> h-unit 16+q;
    // j==5 -> lg (q==0 only); j==6 -> sg (q==0); j==7 -> bias (q==0).
    half8 af[6];
    {
        const int m = cloc;
        const int g = m & 3;
        const int u = m >> 2;
        const float scale = (g == 2) ? L2E2 : L2E;
#pragma unroll
        for (int tt = 0; tt < 5; ++tt) {
            const int unit = (tt < 4) ? (4 * u + tt) : (16 + u);
            const int R = g * 20 + unit;
#pragma unroll
            for (int j = 0; j < 8; ++j) {
                float val = 0.0f;
                if (j < 4)        val = W_hh[R * 20 + (4 * q + j)];
                else if (j == 4)  val = W_hh[R * 20 + (16 + q)];
                else if (q == 0) {
                    if (j == 5)      val = W_ih[R * 2 + 0];
                    else if (j == 6) val = W_ih[R * 2 + 1];
                    else             val = b_ih[R] + b_hh[R];
                }
                af[tt][j] = (_Float16)(val * scale);
            }
        }
        // fc tile: row 0 = fc weights in the same k-permutation; rows 1..15 zero.
#pragma unroll
        for (int j = 0; j < 8; ++j) {
            float val = 0.0f;
            if (m == 0) {
                if (j < 4)                 val = fc_w[4 * q + j];
                else if (j == 4)           val = fc_w[16 + q];
                else if (j == 7 && q == 0) val = fc_b[0];
            }
            af[5][j] = (_Float16)val;
        }
    }

    const int C = (N + CL - 1) / CL;
    const int chunk  = (blockIdx.x * WAVES_PB + wid) * 16 + cloc;
    const int gstart = chunk * CL;
    const bool live  = chunk < C;
    const bool qzero = (q == 0);

    const int bid = blockIdx.x, lastb = gridDim.x - 1;
    if (bid == 0) {
        if (wid == 0)
            scan_loop<true , true >(inputs, N, af[0], af[1], af[2], af[3], af[4], af[5],
                                    gstart, qzero, live, out);
        else
            scan_loop<false, true >(inputs, N, af[0], af[1], af[2], af[3], af[4], af[5],
                                    gstart, qzero, live, out);
    } else if (bid == lastb) {
        scan_loop<false, true >(inputs, N, af[0], af[1], af[2], af[3], af[4], af[5],
                                gstart, qzero, live, out);
    } else {
        scan_loop<false, false>(inputs, N, af[0], af[1], af[2], af[3], af[4], af[5],
                                gstart, qzero, live, out);
    }
}

extern "C" void kernel_launch(void* const* d_in, const int* in_sizes, int n_in,
                              void* d_out, int out_size, void* d_ws, size_t ws_size,
                              hipStream_t stream) {
    const float* inputs = (const float*)d_in[0];
    const float* cW_ih  = (const float*)d_in[1];
    const float* cW_hh  = (const float*)d_in[2];
    const float* cb_ih  = (const float*)d_in[3];
    const float* cb_hh  = (const float*)d_in[4];
    const float* cfc_w  = (const float*)d_in[5];
    const float* cfc_b  = (const float*)d_in[6];
    const float* fW_ih  = (const float*)d_in[7];
    const float* fW_hh  = (const float*)d_in[8];
    const float* fb_ih  = (const float*)d_in[9];
    const float* fb_hh  = (const float*)d_in[10];
    const float* ffc_w  = (const float*)d_in[11];
    const float* ffc_b  = (const float*)d_in[12];
    const int*   is_conv = (const int*)d_in[13];
    float* out = (float*)d_out;

    const int N = in_sizes[0];
    const int C = (N + CL - 1) / CL;                 // chunks (32768 at N=1M)
    const int blocks = (C + 64 - 1) / 64;            // 64 chunks per block -> 512
    lstm_mfma_kernel<<<blocks, BLOCK, 0, stream>>>(
        inputs, N, cW_ih, cW_hh, cb_ih, cb_hh, cfc_w, cfc_b,
        fW_ih, fW_hh, fb_ih, fb_hh, ffc_w, ffc_b, is_conv, out);
}

// Round 10
// 113.269 us; speedup vs baseline: 5.0020x; 1.0420x over previous
//
#include <hip/hip_runtime.h>
#include <math.h>

// LSTM learned-optimizer scan, MFMA formulation v8 — shuffle-free, CL=64/WU=27.
// Per wave: 16 chunks; per step one 96x32 x 32x16 f16 matmul (5 gate tiles +
// 1 fc tile). k-dimension permuted so slots k=8q..8q+7 are exactly the
// features lane (cloc,q) computes itself: units {4q..4q+3, 16+q} + (lg,sg,1)
// in q==0's spare slots. B is assembled from the lane's OWN registers via
// v_cvt_pkrtz — no LDS, no shuffles, no barriers in the recurrence.
// Issue-bound model (R9): wall ∝ waves×ST ∝ 1+(WU+1)/CL; CL=64 cuts total
// issue 23% vs CL=32 at the cost of 1 wave/SIMD (chain ~130 cyc << 490-cyc
// issue budget, so still issue-bound).

#define CL    64            // outputs per chunk
#define WU    27            // warm-up steps; (WU+1)%4==0 for output grouping
#define ST    (WU + CL + 1) // 92 steps; outputs exit fc tile one step late
#define BLOCK 256
#define WAVES_PB 4

typedef _Float16 half8 __attribute__((ext_vector_type(8)));
typedef __fp16   fp16x2 __attribute__((ext_vector_type(2)));   // cvt_pkrtz return type
typedef float  float4_t __attribute__((ext_vector_type(4)));

union B8 { half8 v; fp16x2 p[4]; };

#define L2E   1.4426950408889634f
#define L2E2  2.8853900817779268f
#define LOGSC 0.09902102579427789f   // log2(.) * ln2/7

__device__ __forceinline__ int clampi(int v, int lo, int hi) {
    return v < lo ? lo : (v > hi ? hi : v);
}

// d = [i,f,g,o] pre-scaled by log2e (g by 2*log2e).
// cn = f*c + i*g with one rcp: (c*pi*pg + (1-eg)*pf) * rcp(pf*pi*pg).
#define ACT(dv, cv, hv) do {                                                   \
    const float ei = __builtin_amdgcn_exp2f(-(dv)[0]);                         \
    const float ef = __builtin_amdgcn_exp2f(-(dv)[1]);                         \
    const float eg = __builtin_amdgcn_exp2f(-(dv)[2]);                         \
    const float eo = __builtin_amdgcn_exp2f(-(dv)[3]);                         \
    const float pi_ = 1.0f + ei;                                               \
    const float pf_ = 1.0f + ef;                                               \
    const float pg_ = 1.0f + eg;                                               \
    const float pig = pi_ * pg_;                                               \
    float cn = fmaf((cv), pig, (1.0f - eg) * pf_)                              \
             * __builtin_amdgcn_rcpf(pf_ * pig);                               \
    if (EARLY) cn *= keep;                                                     \
    (cv) = cn;                                                                 \
    const float ec = __builtin_amdgcn_exp2f(cn * -L2E2);                       \
    float hh = (1.0f - ec) * __builtin_amdgcn_rcpf((1.0f + eo) * (1.0f + ec)); \
    if (EARLY) hh *= keep;                                                     \
    (hv) = hh;                                                                 \
} while (0)

template<bool EARLY, bool CLAMP>
__device__ __forceinline__ void scan_loop(
    const float* __restrict__ inputs, int N,
    half8 a0, half8 a1, half8 a2, half8 a3, half8 a4, half8 a5,
    int gstart, bool qzero, bool live,
    float* __restrict__ out)
{
    float c0 = 0.f, c1 = 0.f, c2 = 0.f, c3 = 0.f, c4 = 0.f;
    const int t0 = gstart - WU;
    const float4_t zacc = {0.f, 0.f, 0.f, 0.f};
    const float onq = qzero ? 1.0f : 0.0f;

    // s=0 features (h = 0).
    float xc = inputs[CLAMP ? clampi(t0, 0, N - 1) : t0];
    float lg0 = fmaxf(__builtin_amdgcn_logf(fabsf(xc) + 1e-7f) * LOGSC, -1.0f);
    float sg0 = fminf(fmaxf(lg0 * 1096.6331584284585f, -1.0f), 1.0f);
    B8 bb;
    bb.p[0] = __builtin_amdgcn_cvt_pkrtz(0.f, 0.f);
    bb.p[1] = __builtin_amdgcn_cvt_pkrtz(0.f, 0.f);
    bb.p[2] = __builtin_amdgcn_cvt_pkrtz(0.f, qzero ? lg0 : 0.f);
    bb.p[3] = __builtin_amdgcn_cvt_pkrtz(qzero ? sg0 : 0.f, onq);
    float xn = inputs[CLAMP ? clampi(t0 + 1, 0, N - 1) : (t0 + 1)];

    for (int su = 0; su < ST; su += 4) {
        float4_t og;
#pragma unroll
        for (int k4 = 0; k4 < 4; ++k4) {
            const int s = su + k4;
            const half8 b = bb.v;

            // Features for s+1 — off the recurrence chain.
            float lg = fmaxf(__builtin_amdgcn_logf(fabsf(xn) + 1e-7f) * LOGSC, -1.0f);
            const float sg = fminf(fmaxf(lg * 1096.6331584284585f, -1.0f), 1.0f);
            xn = inputs[CLAMP ? clampi(t0 + s + 2, 0, N - 1) : (t0 + s + 2)];

            const float4_t d0 = __builtin_amdgcn_mfma_f32_16x16x32_f16(a0, b, zacc, 0, 0, 0);
            const float4_t d1 = __builtin_amdgcn_mfma_f32_16x16x32_f16(a1, b, zacc, 0, 0, 0);
            const float4_t d2 = __builtin_amdgcn_mfma_f32_16x16x32_f16(a2, b, zacc, 0, 0, 0);
            const float4_t d3 = __builtin_amdgcn_mfma_f32_16x16x32_f16(a3, b, zacc, 0, 0, 0);
            const float4_t d4 = __builtin_amdgcn_mfma_f32_16x16x32_f16(a4, b, zacc, 0, 0, 0);
            const float4_t d5 = __builtin_amdgcn_mfma_f32_16x16x32_f16(a5, b, zacc, 0, 0, 0);

            float keep = 1.0f;
            if (EARLY) keep = (gstart + s == WU - 1) ? 0.0f : 1.0f;

            float h0, h1, h2, h3, h4;
            ACT(d0, c0, h0);
            ACT(d1, c1, h1);
            ACT(d2, c2, h2);
            ACT(d3, c3, h3);
            ACT(d4, c4, h4);

            // Rebuild B from own registers (units 4q..4q+3, 16+q, then lg/sg/1).
            bb.p[0] = __builtin_amdgcn_cvt_pkrtz(h0, h1);
            bb.p[1] = __builtin_amdgcn_cvt_pkrtz(h2, h3);
            bb.p[2] = __builtin_amdgcn_cvt_pkrtz(h4, qzero ? lg : 0.f);
            bb.p[3] = __builtin_amdgcn_cvt_pkrtz(qzero ? sg : 0.f, onq);

            og[k4] = d5[0];   // fc . h_{s-1} + fc_b (C/D row 0 -> q==0, reg 0)
        }
        // outputs j = s-(WU+1); su = 28..88 -> 16 group-aligned float4 stores
        if (su >= WU + 1) {
            if (qzero && live)
                *(float4_t*)(out + (gstart + su - (WU + 1))) = og;
        }
    }
}

__global__ __launch_bounds__(BLOCK, 1) void lstm_mfma_kernel(
    const float* __restrict__ inputs, int N,
    const float* __restrict__ cW_ih, const float* __restrict__ cW_hh,
    const float* __restrict__ cb_ih, const float* __restrict__ cb_hh,
    const float* __restrict__ cfc_w, const float* __restrict__ cfc_b,
    const float* __restrict__ fW_ih, const float* __restrict__ fW_hh,
    const float* __restrict__ fb_ih, const float* __restrict__ fb_hh,
    const float* __restrict__ ffc_w, const float* __restrict__ ffc_b,
    const int*   __restrict__ is_conv,
    float* __restrict__ out)
{
    const bool conv = (is_conv[0] != 0);
    const float* W_ih = conv ? cW_ih : fW_ih;
    const float* W_hh = conv ? cW_hh : fW_hh;
    const float* b_ih = conv ? cb_ih : fb_ih;
    const float* b_hh = conv ? cb_hh : fb_hh;
    const float* fc_w = conv ? cfc_w : ffc_w;
    const float* fc_b = conv ? cfc_b : ffc_b;

    const int tid  = threadIdx.x;
    const int lane = tid & 63;
    const int wid  = tid >> 6;
    const int cloc = lane & 15;       // chunk column (= MFMA n, = A row m)
    const int q    = lane >> 4;       // quad: A/B k-group, C/D row-group

    // ---- A fragments (VGPR-resident), k-permuted.
    // Row m of tile tt: gate g = m&3, unit = (tt<4 ? 4*(m>>2)+tt : 16+(m>>2)).
    // Column k = 8q+j holds feature: j<4 -> h-unit 4q+j; j==4 -> h-unit 16+q;
    // j==5 -> lg (q==0 only); j==6 -> sg (q==0); j==7 -> bias (q==0).
    half8 af[6];
    {
        const int m = cloc;
        const int g = m & 3;
        const int u = m >> 2;
        const float scale = (g == 2) ? L2E2 : L2E;
#pragma unroll
        for (int tt = 0; tt < 5; ++tt) {
            const int unit = (tt < 4) ? (4 * u + tt) : (16 + u);
            const int R = g * 20 + unit;
#pragma unroll
            for (int j = 0; j < 8; ++j) {
                float val = 0.0f;
                if (j < 4)        val = W_hh[R * 20 + (4 * q + j)];
                else if (j == 4)  val = W_hh[R * 20 + (16 + q)];
                else if (q == 0) {
                    if (j == 5)      val = W_ih[R * 2 + 0];
                    else if (j == 6) val = W_ih[R * 2 + 1];
                    else             val = b_ih[R] + b_hh[R];
                }
                af[tt][j] = (_Float16)(val * scale);
            }
        }
        // fc tile: row 0 = fc weights in the same k-permutation; rows 1..15 zero.
#pragma unroll
        for (int j = 0; j < 8; ++j) {
            float val = 0.0f;
            if (m == 0) {
                if (j < 4)                 val = fc_w[4 * q + j];
                else if (j == 4)           val = fc_w[16 + q];
                else if (j == 7 && q == 0) val = fc_b[0];
            }
            af[5][j] = (_Float16)val;
        }
    }

    const int C = (N + CL - 1) / CL;
    const int chunk  = (blockIdx.x * WAVES_PB + wid) * 16 + cloc;
    const int gstart = chunk * CL;
    const bool live  = chunk < C;
    const bool qzero = (q == 0);

    const int bid = blockIdx.x, lastb = gridDim.x - 1;
    if (bid == 0) {
        if (wid == 0)
            scan_loop<true , true >(inputs, N, af[0], af[1], af[2], af[3], af[4], af[5],
                                    gstart, qzero, live, out);
        else
            scan_loop<false, true >(inputs, N, af[0], af[1], af[2], af[3], af[4], af[5],
                                    gstart, qzero, live, out);
    } else if (bid == lastb) {
        scan_loop<false, true >(inputs, N, af[0], af[1], af[2], af[3], af[4], af[5],
                                gstart, qzero, live, out);
    } else {
        scan_loop<false, false>(inputs, N, af[0], af[1], af[2], af[3], af[4], af[5],
                                gstart, qzero, live, out);
    }
}

extern "C" void kernel_launch(void* const* d_in, const int* in_sizes, int n_in,
                              void* d_out, int out_size, void* d_ws, size_t ws_size,
                              hipStream_t stream) {
    const float* inputs = (const float*)d_in[0];
    const float* cW_ih  = (const float*)d_in[1];
    const float* cW_hh  = (const float*)d_in[2];
    const float* cb_ih  = (const float*)d_in[3];
    const float* cb_hh  = (const float*)d_in[4];
    const float* cfc_w  = (const float*)d_in[5];
    const float* cfc_b  = (const float*)d_in[6];
    const float* fW_ih  = (const float*)d_in[7];
    const float* fW_hh  = (const float*)d_in[8];
    const float* fb_ih  = (const float*)d_in[9];
    const float* fb_hh  = (const float*)d_in[10];
    const float* ffc_w  = (const float*)d_in[11];
    const float* ffc_b  = (const float*)d_in[12];
    const int*   is_conv = (const int*)d_in[13];
    float* out = (float*)d_out;

    const int N = in_sizes[0];
    const int C = (N + CL - 1) / CL;                 // chunks (16384 at N=1M)
    const int blocks = (C + 64 - 1) / 64;            // 64 chunks per block -> 256
    lstm_mfma_kernel<<<blocks, BLOCK, 0, stream>>>(
        inputs, N, cW_ih, cW_hh, cb_ih, cb_hh, cfc_w, cfc_b,
        fW_ih, fW_hh, fb_ih, fb_hh, ffc_w, ffc_b, is_conv, out);
}